// Round 2
// baseline (73896.198 us; speedup 1.0000x reference)
//
#include <hip/hip_runtime.h>
#include <hip/hip_cooperative_groups.h>
#include <math.h>

namespace cg = cooperative_groups;

#define DEV __device__ __forceinline__

constexpr int B = 8, T = 128, V = 32000, A = 64, D = 256, NS = 16, S = 128, H = 4, HD = 64;
constexpr int D2 = 2 * D;  // 512

DEV float sigm(float x) { return 1.0f / (1.0f + expf(-x)); }
DEV float geluf(float x) { return 0.5f * x * (1.0f + erff(x * 0.7071067811865476f)); }

// ---------------- one-time setup kernels ----------------

__global__ __launch_bounds__(256) void k_setup(const float* __restrict__ aimp,
                                               const float* __restrict__ cmix,
                                               const float* __restrict__ bind,
                                               float* __restrict__ iw, float* __restrict__ cwv,
                                               float* __restrict__ sigbind) {
  int tid = threadIdx.x;
  if (tid < 64) {
    float v = aimp[tid];
    float m = v;
    #pragma unroll
    for (int o = 32; o > 0; o >>= 1) m = fmaxf(m, __shfl_xor(m, o, 64));
    float e = expf(v - m);
    float s = e;
    #pragma unroll
    for (int o = 32; o > 0; o >>= 1) s += __shfl_xor(s, o, 64);
    iw[tid] = e / s;
  }
  if (tid == 0) {
    float a = cmix[0], b = cmix[1], m = fmaxf(a, b);
    float ea = expf(a - m), eb = expf(b - m);
    cwv[0] = ea / (ea + eb);
    cwv[1] = eb / (ea + eb);
  }
  for (int i = tid; i < NS * D; i += 256) sigbind[i] = sigm(bind[i]);
}

__global__ __launch_bounds__(256) void k_percepts(const int* __restrict__ idx,
                                                  const float* __restrict__ emb,
                                                  const float* __restrict__ pos,
                                                  float* __restrict__ P) {
  int i = blockIdx.x * 256 + threadIdx.x;
  if (i < B * T * D) {
    int d = i & (D - 1);
    int bt = i / D;
    int t = bt & (T - 1);
    P[i] = emb[(size_t)idx[bt] * D + d] + pos[t * D + d];
  }
}

// cvec[j] = sum_v ba2[v]*Wfb[v,j] + bfb[j]
__global__ __launch_bounds__(256) void k_cvec(const float* __restrict__ Wfb,
                                              const float* __restrict__ ba2,
                                              const float* __restrict__ bfb,
                                              float* __restrict__ cvec) {
  int j = blockIdx.x, tid = threadIdx.x;
  float s = 0.f;
  for (int v = tid; v < V; v += 256) s += ba2[v] * Wfb[(size_t)v * D + j];
  __shared__ float red[256];
  red[tid] = s;
  __syncthreads();
  for (int o = 128; o > 0; o >>= 1) {
    if (tid < o) red[tid] += red[tid + o];
    __syncthreads();
  }
  if (tid == 0) cvec[j] = red[0] + bfb[j];
}

// M partials (split-K over 8 v-chunks of 4000)
__global__ __launch_bounds__(256) void k_mpart(const float* __restrict__ Wa2,
                                               const float* __restrict__ Wfb,
                                               float* __restrict__ part) {
  int it = blockIdx.y;  // 0..15 : 32 rows each
  int vc = blockIdx.x;  // 0..7  : 4000 v each
  int j = threadIdx.x;
  int i0 = it * 32, v0 = vc * 4000;
  __shared__ float a_l[32 * 125];
  float acc[32];
  #pragma unroll
  for (int r = 0; r < 32; r++) acc[r] = 0.f;
  for (int vb = 0; vb < 4000; vb += 125) {
    for (int l = threadIdx.x; l < 32 * 125; l += 256) {
      int r = l / 125, c = l - r * 125;
      a_l[l] = Wa2[(size_t)(i0 + r) * V + v0 + vb + c];
    }
    __syncthreads();
    for (int c = 0; c < 125; c++) {
      float w = Wfb[(size_t)(v0 + vb + c) * D + j];
      #pragma unroll
      for (int r = 0; r < 32; r++) acc[r] += a_l[r * 125 + c] * w;
    }
    __syncthreads();
  }
  for (int r = 0; r < 32; r++) part[((size_t)vc * D2 + i0 + r) * D + j] = acc[r];
}

__global__ __launch_bounds__(256) void k_mreduce(const float* __restrict__ part,
                                                 float* __restrict__ M) {
  int i = blockIdx.x, j = threadIdx.x;
  float s = 0.f;
  for (int vc = 0; vc < 8; vc++) s += part[((size_t)vc * D2 + i) * D + j];
  M[i * D + j] = s;
}

// C[I x 256] = A[I x 256] @ Bm[256 x 256]; grid = I/8 blocks, 256 threads
__global__ __launch_bounds__(256) void k_gemmK256(const float* __restrict__ Am,
                                                  const float* __restrict__ Bm,
                                                  float* __restrict__ C, int I) {
  int r0 = blockIdx.x * 8;
  int tid = threadIdx.x;
  __shared__ float a_l[8][256];
  for (int i = tid; i < 8 * 256; i += 256) a_l[i >> 8][i & 255] = Am[(r0 + (i >> 8)) * 256 + (i & 255)];
  __syncthreads();
  float acc[8] = {0, 0, 0, 0, 0, 0, 0, 0};
  for (int k = 0; k < 256; k++) {
    float bv = Bm[k * 256 + tid];
    #pragma unroll
    for (int r = 0; r < 8; r++) acc[r] += a_l[r][k] * bv;
  }
  for (int r = 0; r < 8; r++) C[(r0 + r) * 256 + tid] = acc[r];
}

// out[j] = sum_k a[k]*Bm[k,j] + bias[j]   (1 block, 256 threads)
__global__ __launch_bounds__(256) void k_vecmat(const float* __restrict__ a,
                                                const float* __restrict__ Bm,
                                                const float* __restrict__ bias,
                                                float* __restrict__ out) {
  int tid = threadIdx.x;
  __shared__ float a_l[256];
  a_l[tid] = a[tid];
  __syncthreads();
  float acc = 0.f;
  for (int k = 0; k < 256; k++) acc += a_l[k] * Bm[k * 256 + tid];
  out[tid] = acc + bias[tid];
}

// ---------------- the persistent cooperative kernel ----------------

struct PP {
  const float *Wsens, *bsens, *sigbind, *anet, *Wc, *bc, *Wg, *bg, *lng, *lnb, *cw, *iw;
  const float *Wq, *bq, *Wk, *bk, *Wv, *bv, *Wo, *bo, *Wmg, *WoMg, *cvec2, *mlng, *mlnb;
  const float *Wa1, *ba1, *M2, *cvec3, *cvec4, *P, *pW;
  float *agents, *u, *psum, *consbuf, *qbuf, *recraw, *val, *psumv, *hbuf, *mod, *KcT, *Vc, *Hall;
};

__global__ __launch_bounds__(512) void k_persist(PP p) {
  cg::grid_group grid = cg::this_grid();
  const int bid = blockIdx.x;   // 0..255
  const int tid = threadIdx.x;  // 0..511
  const int gsize = 256 * 512;
  const int gid = bid * 512 + tid;

  __shared__ float sm[10240];  // 40 KB, aliased per phase

  // ---- INIT: zero agents; mod0 = P0*(1+sigm(cvec4 + pW[:,0])) ----
  for (int i = gid; i < B * A * D; i += gsize) p.agents[i] = 0.f;
  for (int i = gid; i < B * D; i += gsize) {
    int b = i >> 8, j = i & 255;
    float fg = sigm(p.cvec4[j] + p.pW[(b * T + 0) * D + j]);
    p.mod[i] = p.P[(b * T + 0) * D + j] * (1.f + fg);
  }
  grid.sync();

  for (int t = 0; t < T; t++) {
    // ======== PH_SENS: agents[b, :16] += sens ========
    {
      int b = bid >> 5, g = bid & 31;
      int c0 = g * 128;
      float* mod_l = sm;         // 256
      float* part = sm + 4096;   // 512
      if (tid < 256) mod_l[tid] = p.mod[b * D + tid];
      __syncthreads();
      int kp = tid >> 7, cl = tid & 127;
      int col = c0 + cl;
      float acc = 0.f;
      for (int kk = 0; kk < 64; kk++) {
        int k = kp * 64 + kk;
        acc += mod_l[k] * p.Wsens[k * (NS * D) + col];
      }
      part[kp * 128 + cl] = acc;
      __syncthreads();
      if (tid < 128) {
        int c = c0 + tid;
        float s = part[tid] + part[128 + tid] + part[256 + tid] + part[384 + tid];
        float sens = (s + p.bsens[c]) * p.sigbind[c];
        int j = c >> 8, d = c & 255;
        p.agents[(b * A + j) * D + d] += sens;
      }
    }
    grid.sync();

    // ======== PH_GEMM: inter + cand/gate + u (pre-LN) + psum ========
    {
      int rg = bid >> 3, cgp = bid & 7;
      int b = rg >> 2, a0 = (rg & 3) * 16;
      int ch = cgp >> 2, jc0 = (cgp & 3) * 64;
      float* ag16 = sm;            // 4096
      float* inter_l = sm + 4096;  // 4096
      float* anet_l = sm + 8192;   // 1024
      float2* red2 = (float2*)(sm + 9216);  // 512 float2
      for (int i = tid; i < 4096; i += 512) ag16[i] = p.agents[(b * A + a0) * D + i];
      for (int i = tid; i < 1024; i += 512) anet_l[i] = p.anet[ch * 4096 + a0 * 64 + i];
      __syncthreads();
      // inter rows a0..a0+15 for this channel
      {
        int d = tid & 255, rh = tid >> 8;
        float acc[8];
        #pragma unroll
        for (int r = 0; r < 8; r++) acc[r] = 0.f;
        for (int j = 0; j < 64; j++) {
          float agv = p.agents[(b * A + j) * D + d];
          #pragma unroll
          for (int r = 0; r < 8; r++) acc[r] += anet_l[(rh * 8 + r) * 64 + j] * agv;
        }
        #pragma unroll
        for (int r = 0; r < 8; r++) inter_l[(rh * 8 + r) * 256 + d] = acc[r];
      }
      __syncthreads();
      // GEMM: 16 rows x 64 cols (float2 per thread)
      {
        int rr = tid >> 5, jp = tid & 31;
        int j0 = jc0 + jp * 2;
        const float2* Wc2 = (const float2*)(p.Wc + ch * 65536);
        const float2* Wg2 = (const float2*)(p.Wg + ch * 131072);
        float2 ca = {0.f, 0.f}, ga = {0.f, 0.f};
        int jh = j0 >> 1;
        for (int k = 0; k < 256; k++) {
          float iv = inter_l[rr * 256 + k];
          float av = ag16[rr * 256 + k];
          float2 wc = Wc2[k * 128 + jh];
          float2 wg = Wg2[k * 128 + jh];
          ca.x += iv * wc.x; ca.y += iv * wc.y;
          ga.x += av * wg.x; ga.y += av * wg.y;
        }
        for (int k = 0; k < 256; k++) {
          float iv = inter_l[rr * 256 + k];
          float2 wg = Wg2[(256 + k) * 128 + jh];
          ga.x += iv * wg.x; ga.y += iv * wg.y;
        }
        int row = rg * 16 + rr;
        float candx = geluf(ca.x + p.bc[ch * 256 + j0]);
        float candy = geluf(ca.y + p.bc[ch * 256 + j0 + 1]);
        float gatex = sigm(ga.x + p.bg[ch * 256 + j0]);
        float gatey = sigm(ga.y + p.bg[ch * 256 + j0 + 1]);
        float ax = ag16[rr * 256 + j0], ay = ag16[rr * 256 + j0 + 1];
        float ux = gatex * candx + (1.f - gatex) * ax;
        float uy = gatey * candy + (1.f - gatey) * ay;
        ((float2*)p.u)[((ch * 512 + row) * 256 + j0) >> 1] = make_float2(ux, uy);
        red2[tid] = make_float2(ux + uy, ux * ux + uy * uy);
        __syncthreads();
        if (jp == 0) {
          float s = 0.f, q = 0.f;
          #pragma unroll
          for (int jj = 0; jj < 32; jj++) {
            float2 v = red2[rr * 32 + jj];
            s += v.x; q += v.y;
          }
          p.psum[((ch * 512 + row) * 4 + (cgp & 3)) * 2 + 0] = s;
          p.psum[((ch * 512 + row) * 4 + (cgp & 3)) * 2 + 1] = q;
        }
      }
    }
    grid.sync();

    // ======== PH_LN: LN both channels + cw mix -> agents ========
    {
      int r = bid * 2 + (tid >> 8);
      int j = tid & 255;
      float s0 = 0.f, q0 = 0.f, s1 = 0.f, q1 = 0.f;
      #pragma unroll
      for (int cgi = 0; cgi < 4; cgi++) {
        s0 += p.psum[((0 * 512 + r) * 4 + cgi) * 2 + 0];
        q0 += p.psum[((0 * 512 + r) * 4 + cgi) * 2 + 1];
        s1 += p.psum[((512 + r) * 4 + cgi) * 2 + 0];
        q1 += p.psum[((512 + r) * 4 + cgi) * 2 + 1];
      }
      float u0 = p.u[(0 * 512 + r) * 256 + j];
      float u1 = p.u[(512 + r) * 256 + j];
      float m0 = s0 * (1.f / 256.f), v0 = q0 * (1.f / 256.f) - m0 * m0;
      float m1 = s1 * (1.f / 256.f), v1 = q1 * (1.f / 256.f) - m1 * m1;
      float ln0 = (u0 - m0) * rsqrtf(v0 + 1e-5f) * p.lng[j] + p.lnb[j];
      float ln1 = (u1 - m1) * rsqrtf(v1 + 1e-5f) * p.lng[256 + j] + p.lnb[256 + j];
      p.agents[r * 256 + j] = p.cw[0] * ln0 + p.cw[1] * ln1;
    }
    grid.sync();

    // ======== PH_Q: cons + q ========
    if (bid < 32) {
      int b = bid >> 2, cgp = bid & 3;
      float* part = sm;           // 512
      float* cons_l = sm + 1024;  // 256
      {
        int k = tid & 255, ap = tid >> 8;
        float acc = 0.f;
        for (int a = ap * 32; a < ap * 32 + 32; a++)
          acc += p.iw[a] * p.agents[(b * A + a) * D + k];
        part[ap * 256 + k] = acc;
      }
      __syncthreads();
      if (tid < 256) {
        cons_l[tid] = part[tid] + part[256 + tid];
        if (cgp == 0) p.consbuf[b * 256 + tid] = cons_l[tid];
      }
      __syncthreads();
      {
        int cl = tid & 63, kp = tid >> 6;
        int col = cgp * 64 + cl;
        float acc = 0.f;
        for (int k = kp * 32; k < kp * 32 + 32; k++) acc += cons_l[k] * p.Wq[k * 256 + col];
        part[kp * 64 + cl] = acc;
      }
      __syncthreads();
      if (tid < 64) {
        int col = cgp * 64 + tid;
        float s = 0.f;
        #pragma unroll
        for (int kp = 0; kp < 8; kp++) s += part[kp * 64 + tid];
        p.qbuf[b * 256 + col] = s + p.bq[col];
      }
    }
    grid.sync();

    // ======== PH_ATT: scores/softmax/rec per (b,h) ========
    if (bid < 32 && t > 0) {
      int b = bid >> 2, h = bid & 3;
      float* q_l = sm;          // 64
      float* sc_l = sm + 128;   // 128
      float* den_l = sm + 512;  // 1
      if (tid < 64) q_l[tid] = p.qbuf[b * 256 + h * 64 + tid];
      __syncthreads();
      if (tid < 128 && tid < t) {
        int s = tid;
        float acc = 0.f;
        #pragma unroll 8
        for (int e = 0; e < 64; e++) acc += q_l[e] * p.KcT[((b * 4 + h) * 64 + e) * 128 + s];
        sc_l[s] = acc * 0.125f;
      }
      __syncthreads();
      if (tid < 64) {
        float m = -1e30f;
        for (int s = tid; s < t; s += 64) m = fmaxf(m, sc_l[s]);
        #pragma unroll
        for (int o = 32; o > 0; o >>= 1) m = fmaxf(m, __shfl_xor(m, o, 64));
        float den = 0.f;
        for (int s = tid; s < t; s += 64) {
          float e = expf(sc_l[s] - m);
          sc_l[s] = e;
          den += e;
        }
        #pragma unroll
        for (int o = 32; o > 0; o >>= 1) den += __shfl_xor(den, o, 64);
        if (tid == 0) den_l[0] = den;
      }
      __syncthreads();
      if (tid < 64) {
        int d = tid;
        float acc = 0.f;
        for (int s = 0; s < t; s++) acc += sc_l[s] * p.Vc[(b * S + s) * D + h * 64 + d];
        p.recraw[b * 256 + h * 64 + d] = acc / den_l[0];
      }
    }
    grid.sync();

    // ======== PH_OMG: o, mg, val, psumv ========
    if (bid < 64 && t > 0) {
      int b = bid >> 3, cgp = bid & 7;
      int j0 = cgp * 32;
      float* rr_l = sm;             // 256
      float* cons_l2 = sm + 256;    // 256
      float* partO = sm + 1024;     // 512
      float* partM = sm + 1536;     // 512
      float* partW = sm + 2048;     // 512
      float* vred = sm + 2560;      // 32
      float* v2red = sm + 2600;     // 32
      if (tid < 256) {
        rr_l[tid] = p.recraw[b * 256 + tid];
        cons_l2[tid] = p.consbuf[b * 256 + tid];
      }
      __syncthreads();
      {
        int cl = tid & 31, kp = tid >> 5;  // kp 0..15
        int col = j0 + cl;
        float aO = 0.f, aM = 0.f, aW = 0.f;
        for (int k = kp * 16; k < kp * 16 + 16; k++) {
          aO += rr_l[k] * p.Wo[k * 256 + col];
          aM += cons_l2[k] * p.Wmg[k * 256 + col];
          aW += rr_l[k] * p.WoMg[k * 256 + col];
        }
        partO[kp * 32 + cl] = aO;
        partM[kp * 32 + cl] = aM;
        partW[kp * 32 + cl] = aW;
      }
      __syncthreads();
      if (tid < 32) {
        int col = j0 + tid;
        float o = p.bo[col], mgin = p.cvec2[col];
        #pragma unroll
        for (int kp = 0; kp < 16; kp++) {
          o += partO[kp * 32 + tid];
          mgin += partM[kp * 32 + tid] + partW[kp * 32 + tid];
        }
        float mg = sigm(mgin);
        float vv = cons_l2[col] + mg * o;
        p.val[b * 256 + col] = vv;
        vred[tid] = vv;
        v2red[tid] = vv * vv;
      }
      __syncthreads();
      if (tid == 0) {
        float s = 0.f, q = 0.f;
        #pragma unroll
        for (int i = 0; i < 32; i++) { s += vred[i]; q += v2red[i]; }
        p.psumv[(b * 8 + cgp) * 2 + 0] = s;
        p.psumv[(b * 8 + cgp) * 2 + 1] = q;
      }
    }
    grid.sync();

    // ======== PH_CF_KVH: cf (mem-LN), K/V cache, h ========
    {
      int b = bid >> 5, cgp = bid & 31;
      float* cf_l = sm;          // 256
      float* part = sm + 1024;   // 512
      if (tid < 256) {
        float cfv;
        if (t > 0) {
          float vv = p.val[b * 256 + tid];
          float s1 = 0.f, s2 = 0.f;
          #pragma unroll
          for (int g = 0; g < 8; g++) {
            s1 += p.psumv[(b * 8 + g) * 2 + 0];
            s2 += p.psumv[(b * 8 + g) * 2 + 1];
          }
          float m = s1 * (1.f / 256.f), var = s2 * (1.f / 256.f) - m * m;
          cfv = (vv - m) * rsqrtf(var + 1e-5f) * p.mlng[tid] + p.mlnb[tid];
        } else {
          cfv = p.consbuf[b * 256 + tid];
        }
        cf_l[tid] = cfv;
      }
      __syncthreads();
      {
        int kp = tid >> 5, task = tid & 31;  // kp 0..15
        float acc = 0.f;
        if (task < 8) {
          int col = cgp * 8 + task;
          for (int k = kp * 16; k < kp * 16 + 16; k++) acc += cf_l[k] * p.Wk[k * 256 + col];
        } else if (task < 16) {
          int col = cgp * 8 + (task - 8);
          for (int k = kp * 16; k < kp * 16 + 16; k++) acc += cf_l[k] * p.Wv[k * 256 + col];
        } else {
          int hc = cgp * 16 + (task - 16);
          for (int k = kp * 16; k < kp * 16 + 16; k++) acc += cf_l[k] * p.Wa1[k * 512 + hc];
        }
        part[kp * 32 + task] = acc;
      }
      __syncthreads();
      if (tid < 32) {
        int task = tid;
        float s = 0.f;
        #pragma unroll
        for (int kp = 0; kp < 16; kp++) s += part[kp * 32 + task];
        if (task < 8) {
          int col = cgp * 8 + task;
          float kk = s + p.bk[col];
          int h = col >> 6, e = col & 63;
          p.KcT[((b * 4 + h) * 64 + e) * 128 + t] = kk;
        } else if (task < 16) {
          int col = cgp * 8 + (task - 8);
          p.Vc[(b * S + t) * D + col] = s + p.bv[col];
        } else {
          int hc = cgp * 16 + (task - 16);
          float hh = geluf(s + p.ba1[hc]);
          p.hbuf[b * 512 + hc] = hh;
          p.Hall[(size_t)(b * T + t) * D2 + hc] = hh;
        }
      }
    }
    grid.sync();

    // ======== PH_FG: fg = sigm(h@M2 + cvec3 + pW[t+1]); mod ========
    if (bid < 32 && t < T - 1) {
      int b = bid >> 2, cgp = bid & 3;
      float* h_l = sm;          // 512
      float* part = sm + 1024;  // 512
      h_l[tid] = p.hbuf[b * 512 + tid];
      __syncthreads();
      {
        int cl = tid & 63, kp = tid >> 6;  // kp 0..7
        int col = cgp * 64 + cl;
        float acc = 0.f;
        for (int k = kp * 64; k < kp * 64 + 64; k++) acc += h_l[k] * p.M2[k * 256 + col];
        part[kp * 64 + cl] = acc;
      }
      __syncthreads();
      if (tid < 64) {
        int col = cgp * 64 + tid;
        float s = 0.f;
        #pragma unroll
        for (int kp = 0; kp < 8; kp++) s += part[kp * 64 + tid];
        s += p.cvec3[col] + p.pW[(b * T + t + 1) * D + col];
        float fg = sigm(s);
        float pt = p.P[(b * T + t + 1) * D + col];
        p.mod[b * 256 + col] = pt * (1.f + fg);
      }
    }
    grid.sync();
  }
}

// final: out[bt, v] = Hall[bt,:] @ Wa2 + ba2
__global__ __launch_bounds__(256) void k_logits(const float* __restrict__ Hall,
                                                const float* __restrict__ Wa2,
                                                const float* __restrict__ ba2,
                                                float* __restrict__ out) {
  int rt = blockIdx.y;
  int v = blockIdx.x * 256 + threadIdx.x;
  const float* hrow = Hall + (size_t)rt * 32 * D2;
  float acc[32];
  float bb = ba2[v];
  #pragma unroll
  for (int r = 0; r < 32; r++) acc[r] = bb;
  for (int k = 0; k < D2; k++) {
    float w = Wa2[(size_t)k * V + v];
    #pragma unroll
    for (int r = 0; r < 32; r++) acc[r] += hrow[r * D2 + k] * w;
  }
  for (int r = 0; r < 32; r++) out[(size_t)(rt * 32 + r) * V + v] = acc[r];
}

// ---------------- launcher ----------------

extern "C" void kernel_launch(void* const* d_in, const int* in_sizes, int n_in,
                              void* d_out, int out_size, void* d_ws, size_t ws_size,
                              hipStream_t stream) {
  const int* idx = (const int*)d_in[0];
  const float* emb = (const float*)d_in[1];
  const float* pos = (const float*)d_in[2];
  const float* Wsens = (const float*)d_in[3];
  const float* bsens = (const float*)d_in[4];
  const float* Wfb = (const float*)d_in[5];
  const float* bfb = (const float*)d_in[6];
  const float* Wfg = (const float*)d_in[7];
  const float* bfg = (const float*)d_in[8];
  const float* bind = (const float*)d_in[9];
  const float* anet = (const float*)d_in[10];
  const float* Wg = (const float*)d_in[11];
  const float* bg = (const float*)d_in[12];
  const float* Wc = (const float*)d_in[13];
  const float* bc = (const float*)d_in[14];
  const float* lng = (const float*)d_in[15];
  const float* lnb = (const float*)d_in[16];
  const float* cmix = (const float*)d_in[17];
  const float* aimp = (const float*)d_in[18];
  const float* Wq = (const float*)d_in[19];
  const float* bq = (const float*)d_in[20];
  const float* Wk = (const float*)d_in[21];
  const float* bk = (const float*)d_in[22];
  const float* Wv = (const float*)d_in[23];
  const float* bv = (const float*)d_in[24];
  const float* Wo = (const float*)d_in[25];
  const float* bo = (const float*)d_in[26];
  const float* Wmg = (const float*)d_in[27];
  const float* bmg = (const float*)d_in[28];
  const float* mlng = (const float*)d_in[29];
  const float* mlnb = (const float*)d_in[30];
  const float* Wa1 = (const float*)d_in[31];
  const float* ba1 = (const float*)d_in[32];
  const float* Wa2 = (const float*)d_in[33];
  const float* ba2 = (const float*)d_in[34];

  float* ws = (float*)d_ws;
  float* M2 = ws;                  // 131072
  float* WoMg = ws + 131072;       // 65536
  float* cvec = ws + 196608;       // 256
  float* cvec2 = ws + 196864;      // 256
  float* cvec3 = ws + 197120;      // 256
  float* cvec4 = ws + 197376;      // 256
  float* iw = ws + 197632;         // 64
  float* cwb = ws + 197696;        // 64
  float* sigbind = ws + 197760;    // 4096
  float* P = ws + 201856;          // 262144
  float* pW = ws + 464000;         // 262144
  float* agents = ws + 726144;     // 131072
  float* u = ws + 857216;          // 262144
  float* psum = ws + 1119360;      // 8192
  float* consbuf = ws + 1127552;   // 2048
  float* qbuf = ws + 1129600;      // 2048
  float* recraw = ws + 1131648;    // 2048
  float* val = ws + 1133696;       // 2048
  float* psumv = ws + 1135744;     // 128
  float* hbuf = ws + 1135872;      // 4096
  float* mod = ws + 1139968;       // 2048
  float* KcT = ws + 1142016;       // 262144
  float* Vc = ws + 1404160;        // 262144
  float* Hall = ws + 1666304;      // 524288
  float* M = ws + 2190592;         // 131072
  float* Mpart = ws + 2321664;     // 1048576  (end 3370240 floats = 13.5 MB)

  k_setup<<<1, 256, 0, stream>>>(aimp, cmix, bind, iw, cwb, sigbind);
  k_percepts<<<dim3((B * T * D + 255) / 256), 256, 0, stream>>>(idx, emb, pos, P);
  k_cvec<<<256, 256, 0, stream>>>(Wfb, ba2, bfb, cvec);
  k_mpart<<<dim3(8, 16), 256, 0, stream>>>(Wa2, Wfb, Mpart);
  k_mreduce<<<512, 256, 0, stream>>>(Mpart, M);
  // M2 = M @ Wfg[0:256]; WoMg = Wo @ Wmg[256:512]; pW = P @ Wfg[256:512]
  k_gemmK256<<<64, 256, 0, stream>>>(M, Wfg, M2, 512);
  k_gemmK256<<<32, 256, 0, stream>>>(Wo, Wmg + 65536, WoMg, 256);
  k_gemmK256<<<128, 256, 0, stream>>>(P, Wfg + 65536, pW, 1024);
  k_vecmat<<<1, 256, 0, stream>>>(bo, Wmg + 65536, bmg, cvec2);
  k_vecmat<<<1, 256, 0, stream>>>(cvec, Wfg, bfg, cvec3);
  k_vecmat<<<1, 256, 0, stream>>>(bfb, Wfg, bfg, cvec4);

  PP prm;
  prm.Wsens = Wsens; prm.bsens = bsens; prm.sigbind = sigbind; prm.anet = anet;
  prm.Wc = Wc; prm.bc = bc; prm.Wg = Wg; prm.bg = bg; prm.lng = lng; prm.lnb = lnb;
  prm.cw = cwb; prm.iw = iw; prm.Wq = Wq; prm.bq = bq; prm.Wk = Wk; prm.bk = bk;
  prm.Wv = Wv; prm.bv = bv; prm.Wo = Wo; prm.bo = bo; prm.Wmg = Wmg; prm.WoMg = WoMg;
  prm.cvec2 = cvec2; prm.mlng = mlng; prm.mlnb = mlnb; prm.Wa1 = Wa1; prm.ba1 = ba1;
  prm.M2 = M2; prm.cvec3 = cvec3; prm.cvec4 = cvec4; prm.P = P; prm.pW = pW;
  prm.agents = agents; prm.u = u; prm.psum = psum; prm.consbuf = consbuf;
  prm.qbuf = qbuf; prm.recraw = recraw; prm.val = val; prm.psumv = psumv;
  prm.hbuf = hbuf; prm.mod = mod; prm.KcT = KcT; prm.Vc = Vc; prm.Hall = Hall;

  void* args[] = {&prm};
  hipLaunchCooperativeKernel((void*)k_persist, dim3(256), dim3(512), args, 0, stream);

  k_logits<<<dim3(125, 32), 256, 0, stream>>>(Hall, Wa2, ba2, (float*)d_out);
}

// Round 3
// 29959.897 us; speedup vs baseline: 2.4665x; 2.4665x over previous
//
#include <hip/hip_runtime.h>
#include <math.h>

#define DEV __device__ __forceinline__

constexpr int B = 8, T = 128, V = 32000, A = 64, D = 256, NS = 16, S = 128, H = 4, HD = 64;
constexpr int D2 = 2 * D;  // 512

DEV float sigm(float x) { return 1.0f / (1.0f + expf(-x)); }
DEV float geluf(float x) { return 0.5f * x * (1.0f + erff(x * 0.7071067811865476f)); }

// ---------------- one-time setup kernels ----------------

__global__ __launch_bounds__(256) void k_setup(const float* __restrict__ aimp,
                                               const float* __restrict__ cmix,
                                               const float* __restrict__ bind,
                                               float* __restrict__ iw, float* __restrict__ cwv,
                                               float* __restrict__ sigbind) {
  int tid = threadIdx.x;
  if (tid < 64) {
    float v = aimp[tid];
    float m = v;
    #pragma unroll
    for (int o = 32; o > 0; o >>= 1) m = fmaxf(m, __shfl_xor(m, o, 64));
    float e = expf(v - m);
    float s = e;
    #pragma unroll
    for (int o = 32; o > 0; o >>= 1) s += __shfl_xor(s, o, 64);
    iw[tid] = e / s;
  }
  if (tid == 0) {
    float a = cmix[0], b = cmix[1], m = fmaxf(a, b);
    float ea = expf(a - m), eb = expf(b - m);
    cwv[0] = ea / (ea + eb);
    cwv[1] = eb / (ea + eb);
  }
  for (int i = tid; i < NS * D; i += 256) sigbind[i] = sigm(bind[i]);
}

__global__ __launch_bounds__(256) void k_percepts(const int* __restrict__ idx,
                                                  const float* __restrict__ emb,
                                                  const float* __restrict__ pos,
                                                  float* __restrict__ P) {
  int i = blockIdx.x * 256 + threadIdx.x;
  if (i < B * T * D) {
    int d = i & (D - 1);
    int bt = i / D;
    int t = bt & (T - 1);
    P[i] = emb[(size_t)idx[bt] * D + d] + pos[t * D + d];
  }
}

__global__ __launch_bounds__(256) void k_cvec(const float* __restrict__ Wfb,
                                              const float* __restrict__ ba2,
                                              const float* __restrict__ bfb,
                                              float* __restrict__ cvec) {
  int j = blockIdx.x, tid = threadIdx.x;
  float s = 0.f;
  for (int v = tid; v < V; v += 256) s += ba2[v] * Wfb[(size_t)v * D + j];
  __shared__ float red[256];
  red[tid] = s;
  __syncthreads();
  for (int o = 128; o > 0; o >>= 1) {
    if (tid < o) red[tid] += red[tid + o];
    __syncthreads();
  }
  if (tid == 0) cvec[j] = red[0] + bfb[j];
}

__global__ __launch_bounds__(256) void k_mpart(const float* __restrict__ Wa2,
                                               const float* __restrict__ Wfb,
                                               float* __restrict__ part) {
  int it = blockIdx.y;
  int vc = blockIdx.x;
  int j = threadIdx.x;
  int i0 = it * 32, v0 = vc * 4000;
  __shared__ float a_l[32 * 125];
  float acc[32];
  #pragma unroll
  for (int r = 0; r < 32; r++) acc[r] = 0.f;
  for (int vb = 0; vb < 4000; vb += 125) {
    for (int l = threadIdx.x; l < 32 * 125; l += 256) {
      int r = l / 125, c = l - r * 125;
      a_l[l] = Wa2[(size_t)(i0 + r) * V + v0 + vb + c];
    }
    __syncthreads();
    for (int c = 0; c < 125; c++) {
      float w = Wfb[(size_t)(v0 + vb + c) * D + j];
      #pragma unroll
      for (int r = 0; r < 32; r++) acc[r] += a_l[r * 125 + c] * w;
    }
    __syncthreads();
  }
  for (int r = 0; r < 32; r++) part[((size_t)vc * D2 + i0 + r) * D + j] = acc[r];
}

__global__ __launch_bounds__(256) void k_mreduce(const float* __restrict__ part,
                                                 float* __restrict__ M) {
  int i = blockIdx.x, j = threadIdx.x;
  float s = 0.f;
  for (int vc = 0; vc < 8; vc++) s += part[((size_t)vc * D2 + i) * D + j];
  M[i * D + j] = s;
}

__global__ __launch_bounds__(256) void k_gemmK256(const float* __restrict__ Am,
                                                  const float* __restrict__ Bm,
                                                  float* __restrict__ C, int I) {
  int r0 = blockIdx.x * 8;
  int tid = threadIdx.x;
  __shared__ float a_l[8][256];
  for (int i = tid; i < 8 * 256; i += 256) a_l[i >> 8][i & 255] = Am[(r0 + (i >> 8)) * 256 + (i & 255)];
  __syncthreads();
  float acc[8] = {0, 0, 0, 0, 0, 0, 0, 0};
  for (int k = 0; k < 256; k++) {
    float bv = Bm[k * 256 + tid];
    #pragma unroll
    for (int r = 0; r < 8; r++) acc[r] += a_l[r][k] * bv;
  }
  for (int r = 0; r < 8; r++) C[(r0 + r) * 256 + tid] = acc[r];
}

__global__ __launch_bounds__(256) void k_vecmat(const float* __restrict__ a,
                                                const float* __restrict__ Bm,
                                                const float* __restrict__ bias,
                                                float* __restrict__ out) {
  int tid = threadIdx.x;
  __shared__ float a_l[256];
  a_l[tid] = a[tid];
  __syncthreads();
  float acc = 0.f;
  for (int k = 0; k < 256; k++) acc += a_l[k] * Bm[k * 256 + tid];
  out[tid] = acc + bias[tid];
}

__global__ __launch_bounds__(256) void k_barinit(unsigned* bars) {
  int i = blockIdx.x * 256 + threadIdx.x;
  if (i < 1024) bars[i] = 0u;
}

// ---------------- barrier helpers ----------------

DEV void fence_rel() { __builtin_amdgcn_fence(__ATOMIC_RELEASE, "agent"); }
DEV void fence_acq() { __builtin_amdgcn_fence(__ATOMIC_ACQUIRE, "agent"); }

DEV unsigned aload(unsigned* p) { return __hip_atomic_load(p, __ATOMIC_RELAXED, __HIP_MEMORY_SCOPE_AGENT); }
DEV void astore(unsigned* p, unsigned v) { __hip_atomic_store(p, v, __ATOMIC_RELAXED, __HIP_MEMORY_SCOPE_AGENT); }
DEV void astore_rel(unsigned* p, unsigned v) { __hip_atomic_store(p, v, __ATOMIC_RELEASE, __HIP_MEMORY_SCOPE_AGENT); }
DEV unsigned aadd(unsigned* p) { return __hip_atomic_fetch_add(p, 1u, __ATOMIC_ACQ_REL, __HIP_MEMORY_SCOPE_AGENT); }

// grid barrier: tree over 8 sub-counters (bars[0..159]: sub s at s*16, root at 128, gen at 144)
DEV void grid_sync(unsigned* gb) {
  __syncthreads();
  if (threadIdx.x == 0) {
    fence_rel();
    unsigned* gen = gb + 144;
    unsigned g = aload(gen);
    unsigned a = aadd(gb + (blockIdx.x & 7) * 16);
    if (a == 31) {
      unsigned r = aadd(gb + 128);
      if (r == 7) {
        for (int s = 0; s < 8; s++) astore(gb + s * 16, 0u);
        astore(gb + 128, 0u);
        astore_rel(gen, g + 1);
      }
    }
    unsigned spins = 0;
    while (aload(gen) == g) {
      __builtin_amdgcn_s_sleep(1);
      if (++spins > (1u << 28)) break;
    }
    fence_acq();
  }
  __syncthreads();
}

// mini barrier among 32 blocks of one group (cnt at mb[0], gen at mb[16])
DEV void mini_sync(unsigned* mb) {
  __syncthreads();
  if (threadIdx.x == 0) {
    fence_rel();
    unsigned g = aload(mb + 16);
    unsigned a = aadd(mb);
    if (a == 31) {
      astore(mb, 0u);
      astore_rel(mb + 16, g + 1);
    } else {
      unsigned spins = 0;
      while (aload(mb + 16) == g) {
        __builtin_amdgcn_s_sleep(1);
        if (++spins > (1u << 28)) break;
      }
    }
    fence_acq();
  }
  __syncthreads();
}

// ---------------- the persistent cooperative kernel ----------------

struct PP {
  const float *Wsens, *bsens, *sigbind, *anet, *Wc, *bc, *Wg, *bg, *lng, *lnb, *cw, *iw;
  const float *Wq, *bq, *Wk, *bk, *Wv, *bv, *Wo, *bo, *Wmg, *WoMg, *cvec2, *mlng, *mlnb;
  const float *Wa1, *ba1, *M2, *cvec3, *cvec4, *P, *pW;
  float *agents, *X, *psumU, *consbuf, *qbuf, *scorebuf, *recbuf, *valps, *cfbuf, *hbuf, *mod, *Kc, *Vc, *Hall;
  unsigned* bars;
};

__global__ __launch_bounds__(512) void k_persist(PP p) {
  const int bid = blockIdx.x;   // 0..255
  const int tid = threadIdx.x;  // 0..511
  const int gid = bid * 512 + tid;
  const int cb = bid & 7;       // chain batch
  const int ci = bid >> 3;      // chain col group 0..31

  __shared__ float sensW[4096];            // [k][16]
  __shared__ float g1W[6144];              // [k][24]
  __shared__ float WqL[2048], WkL[2048], WvL[2048], WoL[2048];  // [k][8]
  __shared__ float Wa1L[4096];             // [k][16]
  __shared__ float scr[5120];              // anet(4096) + Xs(1024) / G1 row tile
  __shared__ float red2[512], red3[512];
  __shared__ float statsl[256];
  __shared__ float m_l[4], den_l[4], val_l[8], vst[2];

  unsigned* gb = p.bars;
  unsigned* mb = p.bars + 256 + cb * 32;

  // ---- load LDS-resident weight slices (once) ----
  for (int idx = tid; idx < 4096; idx += 512)
    sensW[idx] = p.Wsens[(idx >> 4) * 4096 + (bid << 4) + (idx & 15)];
  for (int idx = tid; idx < 6144; idx += 512) {
    int k = idx / 24, c = idx % 24;
    int cglob = (bid & 63) * 24 + c;
    int ch = cglob / 768, sub = cglob % 768;
    float w;
    if (sub < 256) w = p.Wc[ch * 65536 + k * 256 + sub];
    else if (sub < 512) w = p.Wg[ch * 131072 + k * 256 + (sub - 256)];
    else w = p.Wg[ch * 131072 + (256 + k) * 256 + (sub - 512)];
    g1W[idx] = w;
  }
  for (int idx = tid; idx < 2048; idx += 512) {
    int k = idx >> 3, c = idx & 7, cg = ci * 8 + c;
    WqL[idx] = p.Wq[k * 256 + cg];
    WkL[idx] = p.Wk[k * 256 + cg];
    WvL[idx] = p.Wv[k * 256 + cg];
    WoL[idx] = p.Wo[k * 256 + cg];
  }
  for (int idx = tid; idx < 4096; idx += 512) {
    int k = idx >> 4, c = idx & 15;
    Wa1L[idx] = p.Wa1[k * 512 + ci * 16 + c];
  }
  __syncthreads();

  // ---- INIT ----
  p.agents[gid] = 0.f;  // 131072 = gridDim*blockDim exactly
  if (gid < B * D) {
    int b = gid >> 8, j = gid & 255;
    float fg = sigm(p.cvec4[j] + p.pW[(b << 7) * 256 + j]);
    p.mod[gid] = p.P[(b << 7) * 256 + j] * (1.f + fg);
  }
  grid_sync(gb);

  for (int t = 0; t < T; t++) {
    // ======== SENS: agents[b, :16] += sens (this block: cols bid*16..bid*16+15) ========
    {
      int b = tid >> 6, kq = (tid >> 4) & 3, c = tid & 15;
      float acc = 0.f;
      const float* mg = p.mod + b * 256 + kq * 64;
      #pragma unroll 8
      for (int kk = 0; kk < 64; kk++) acc += mg[kk] * sensW[(kq * 64 + kk) * 16 + c];
      red2[tid] = acc;
      __syncthreads();
      if (tid < 128) {
        int b2 = tid >> 4, c2 = tid & 15;
        float s = red2[b2 * 64 + c2] + red2[b2 * 64 + 16 + c2] + red2[b2 * 64 + 32 + c2] +
                  red2[b2 * 64 + 48 + c2];
        int col = (bid << 4) + c2;
        float sens = (s + p.bsens[col]) * p.sigbind[col];
        int j = col >> 8, d = col & 255;
        p.agents[(b2 * 64 + j) * 256 + d] += sens;
      }
    }
    grid_sync(gb);

    // ======== G1: X[512 x 1536] = agents @ [Wc|Wg0|Wg1] (both channels) ========
    {
      int rg = bid >> 6;   // 0..3 -> 128 rows
      int cg = bid & 63;   // 24 cols
      for (int st = 0; st < 8; st++) {
        int row0 = rg * 128 + st * 16;
        for (int idx = tid; idx < 4096; idx += 512) scr[idx] = p.agents[row0 * 256 + idx];
        __syncthreads();
        if (tid < 384) {
          int r = tid / 24, c = tid % 24;
          const float* ar = &scr[r * 256];
          float acc = 0.f;
          #pragma unroll 8
          for (int k = 0; k < 256; k++) acc += ar[k] * g1W[k * 24 + c];
          p.X[(row0 + r) * 1536 + cg * 24 + c] = acc;
        }
        __syncthreads();
      }
    }
    grid_sync(gb);

    // ======== CHAIN (per b: 32 blocks, cols ci*8..ci*8+7) ========
    const int b = cb, i = ci;
    float u0 = 0.f, u1 = 0.f;
    // --- G2 (Y = anet @ Xc/Xg1) + u ---
    for (int ch = 0; ch < 2; ch++) {
      for (int idx = tid; idx < 4096; idx += 512) scr[idx] = p.anet[ch * 4096 + idx];
      for (int idx = tid; idx < 1024; idx += 512) {
        int mat = idx >> 9, j = (idx >> 3) & 63, c = idx & 7;
        scr[4096 + idx] = p.X[(b * 64 + j) * 1536 + ch * 768 + mat * 512 + i * 8 + c];
      }
      __syncthreads();
      int r = tid >> 3, c = tid & 7, cg = i * 8 + c;
      const float* an = &scr[r * 64];
      float yc = 0.f, yg = 0.f;
      #pragma unroll 8
      for (int j = 0; j < 64; j++) {
        float a = an[j];
        yc += a * scr[4096 + j * 8 + c];
        yg += a * scr[4096 + 512 + j * 8 + c];
      }
      float xg0 = p.X[(b * 64 + r) * 1536 + ch * 768 + 256 + cg];
      float agv = p.agents[(b * 64 + r) * 256 + cg];
      float cand = geluf(yc + p.bc[ch * 256 + cg]);
      float gate = sigm(xg0 + yg + p.bg[ch * 256 + cg]);
      float uu = gate * cand + (1.f - gate) * agv;
      if (ch == 0) u0 = uu; else u1 = uu;
      float su = uu, sq = uu * uu;
      su += __shfl_down(su, 4, 64); sq += __shfl_down(sq, 4, 64);
      su += __shfl_down(su, 2, 64); sq += __shfl_down(sq, 2, 64);
      su += __shfl_down(su, 1, 64); sq += __shfl_down(sq, 1, 64);
      if (c == 0) {
        int o = (((b * 2 + ch) * 64 + r) * 32 + i) * 2;
        p.psumU[o] = su;
        p.psumU[o + 1] = sq;
      }
      __syncthreads();
    }
    mini_sync(mb);  // MB0
    // --- LN stats (redundant per block) ---
    if (tid < 128) {
      int ch = tid >> 6, r = tid & 63;
      const float* ps = p.psumU + ((b * 2 + ch) * 64 + r) * 64;
      float s = 0.f, q = 0.f;
      for (int j = 0; j < 32; j++) { s += ps[j * 2]; q += ps[j * 2 + 1]; }
      float mn = s * (1.f / 256.f);
      float var = q * (1.f / 256.f) - mn * mn;
      statsl[tid * 2] = mn;
      statsl[tid * 2 + 1] = rsqrtf(var + 1e-5f);
    }
    __syncthreads();
    // --- LN + mix -> agents ; cons partial ---
    {
      int r = tid >> 3, c = tid & 7, cg = i * 8 + c;
      float ln0 = (u0 - statsl[r * 2]) * statsl[r * 2 + 1] * p.lng[cg] + p.lnb[cg];
      float ln1 = (u1 - statsl[128 + r * 2]) * statsl[128 + r * 2 + 1] * p.lng[256 + cg] + p.lnb[256 + cg];
      float mixed = p.cw[0] * ln0 + p.cw[1] * ln1;
      p.agents[(b * 64 + r) * 256 + cg] = mixed;
      float pc = p.iw[r] * mixed;
      pc += __shfl_xor(pc, 8, 64);
      pc += __shfl_xor(pc, 16, 64);
      pc += __shfl_xor(pc, 32, 64);
      if ((tid & 63) < 8) red3[(tid >> 6) * 8 + c] = pc;
      __syncthreads();
      if (tid < 8) {
        float s = 0.f;
        #pragma unroll
        for (int w = 0; w < 8; w++) s += red3[w * 8 + tid];
        p.consbuf[b * 256 + i * 8 + tid] = s;
      }
    }
    mini_sync(mb);  // MB1
    // --- q ---
    {
      int c = tid & 7, ks = tid >> 3;
      const float* cons = p.consbuf + b * 256;
      float acc = 0.f;
      #pragma unroll
      for (int k = ks * 4; k < ks * 4 + 4; k++) acc += cons[k] * WqL[k * 8 + c];
      red2[tid] = acc;
      __syncthreads();
      if (tid < 8) {
        float s = 0.f;
        for (int j = 0; j < 64; j++) s += red2[j * 8 + tid];
        p.qbuf[b * 256 + i * 8 + tid] = s + p.bq[i * 8 + tid];
      }
    }
    mini_sync(mb);  // MB2
    // --- scores (this block: s = i*4 + 0..3) ---
    if (t > 0) {
      int sl = tid >> 7, h = (tid >> 5) & 3, e2 = tid & 31;
      int s = i * 4 + sl;
      if (s < t) {
        const float* qh = p.qbuf + b * 256 + h * 64;
        const float* kr = p.Kc + ((b << 7) + s) * 256 + h * 64;
        float acc = qh[e2 * 2] * kr[e2 * 2] + qh[e2 * 2 + 1] * kr[e2 * 2 + 1];
        acc += __shfl_down(acc, 16, 64);
        acc += __shfl_down(acc, 8, 64);
        acc += __shfl_down(acc, 4, 64);
        acc += __shfl_down(acc, 2, 64);
        acc += __shfl_down(acc, 1, 64);
        if (e2 == 0) p.scorebuf[((b * 4 + h) << 7) + s] = acc * 0.125f;
      }
    }
    mini_sync(mb);  // MB3
    // --- softmax stats + rec ---
    if (t > 0) {
      int h2 = tid >> 7, sc = tid & 127;
      float v = (sc < t) ? p.scorebuf[((b * 4 + h2) << 7) + sc] : -1e30f;
      float mx = v;
      mx = fmaxf(mx, __shfl_xor(mx, 1, 64));
      mx = fmaxf(mx, __shfl_xor(mx, 2, 64));
      mx = fmaxf(mx, __shfl_xor(mx, 4, 64));
      mx = fmaxf(mx, __shfl_xor(mx, 8, 64));
      mx = fmaxf(mx, __shfl_xor(mx, 16, 64));
      mx = fmaxf(mx, __shfl_xor(mx, 32, 64));
      if ((tid & 63) == 0) red3[tid >> 6] = mx;
      __syncthreads();
      if (tid < 4) m_l[tid] = fmaxf(red3[tid * 2], red3[tid * 2 + 1]);
      __syncthreads();
      float e = (sc < t) ? expf(v - m_l[h2]) : 0.f;
      float se = e;
      se += __shfl_xor(se, 1, 64);
      se += __shfl_xor(se, 2, 64);
      se += __shfl_xor(se, 4, 64);
      se += __shfl_xor(se, 8, 64);
      se += __shfl_xor(se, 16, 64);
      se += __shfl_xor(se, 32, 64);
      if ((tid & 63) == 0) red3[8 + (tid >> 6)] = se;
      __syncthreads();
      if (tid < 4) den_l[tid] = red3[8 + tid * 2] + red3[8 + tid * 2 + 1];
      __syncthreads();
      int c = tid >> 6, lane = tid & 63, cg = i * 8 + c, hh = cg >> 6;
      float pr = 0.f;
      for (int s2 = lane; s2 < t; s2 += 64)
        pr += expf(p.scorebuf[((b * 4 + hh) << 7) + s2] - m_l[hh]) * p.Vc[((b << 7) + s2) * 256 + cg];
      pr += __shfl_down(pr, 32, 64);
      pr += __shfl_down(pr, 16, 64);
      pr += __shfl_down(pr, 8, 64);
      pr += __shfl_down(pr, 4, 64);
      pr += __shfl_down(pr, 2, 64);
      pr += __shfl_down(pr, 1, 64);
      if (lane == 0) p.recbuf[b * 256 + cg] = pr / den_l[hh];
    }
    mini_sync(mb);  // MB4
    // --- o / mg / val ---
    if (t > 0) {
      int c = tid & 7, ks = tid >> 3, cg = i * 8 + c;
      const float* cons = p.consbuf + b * 256;
      const float* rec = p.recbuf + b * 256;
      float po = 0.f, pm = 0.f;
      #pragma unroll
      for (int k = ks * 4; k < ks * 4 + 4; k++) {
        float rv = rec[k];
        po += rv * WoL[k * 8 + c];
        pm += cons[k] * p.Wmg[k * 256 + cg] + rv * p.WoMg[k * 256 + cg];
      }
      red2[tid] = po;
      red3[tid] = pm;
      __syncthreads();
      if (tid < 8) {
        float so = 0.f, sm = 0.f;
        for (int j = 0; j < 64; j++) { so += red2[j * 8 + tid]; sm += red3[j * 8 + tid]; }
        float o = so + p.bo[i * 8 + tid];
        float mg = sigm(sm + p.cvec2[i * 8 + tid]);
        val_l[tid] = cons[i * 8 + tid] + mg * o;
      }
      __syncthreads();
      if (tid == 0) {
        float s = 0.f, q = 0.f;
        #pragma unroll
        for (int j = 0; j < 8; j++) { s += val_l[j]; q += val_l[j] * val_l[j]; }
        p.valps[(b * 32 + i) * 2] = s;
        p.valps[(b * 32 + i) * 2 + 1] = q;
      }
    }
    mini_sync(mb);  // MB5
    // --- cf ---
    {
      if (t > 0) {
        if (tid < 64) {
          float s = 0.f, q = 0.f;
          if (tid < 32) { s = p.valps[(b * 32 + tid) * 2]; q = p.valps[(b * 32 + tid) * 2 + 1]; }
          s += __shfl_xor(s, 1, 64); q += __shfl_xor(q, 1, 64);
          s += __shfl_xor(s, 2, 64); q += __shfl_xor(q, 2, 64);
          s += __shfl_xor(s, 4, 64); q += __shfl_xor(q, 4, 64);
          s += __shfl_xor(s, 8, 64); q += __shfl_xor(q, 8, 64);
          s += __shfl_xor(s, 16, 64); q += __shfl_xor(q, 16, 64);
          s += __shfl_xor(s, 32, 64); q += __shfl_xor(q, 32, 64);
          if (tid == 0) {
            float mn = s * (1.f / 256.f);
            float var = q * (1.f / 256.f) - mn * mn;
            vst[0] = mn;
            vst[1] = rsqrtf(var + 1e-5f);
          }
        }
        __syncthreads();
      }
      if (tid < 8) {
        int cg = i * 8 + tid;
        float cf;
        if (t > 0) cf = (val_l[tid] - vst[0]) * vst[1] * p.mlng[cg] + p.mlnb[cg];
        else cf = p.consbuf[b * 256 + cg];
        p.cfbuf[b * 256 + cg] = cf;
      }
    }
    mini_sync(mb);  // MB6
    // --- K, V, h ---
    {
      int c = tid & 7, ks = tid >> 3;
      const float* cf = p.cfbuf + b * 256;
      float pk = 0.f, pv = 0.f;
      #pragma unroll
      for (int k = ks * 4; k < ks * 4 + 4; k++) {
        float cv = cf[k];
        pk += cv * WkL[k * 8 + c];
        pv += cv * WvL[k * 8 + c];
      }
      red2[tid] = pk;
      red3[tid] = pv;
      __syncthreads();
      if (tid < 8) {
        float sk = 0.f, sv = 0.f;
        for (int j = 0; j < 64; j++) { sk += red2[j * 8 + tid]; sv += red3[j * 8 + tid]; }
        p.Kc[((b << 7) + t) * 256 + i * 8 + tid] = sk + p.bk[i * 8 + tid];
        p.Vc[((b << 7) + t) * 256 + i * 8 + tid] = sv + p.bv[i * 8 + tid];
      }
      __syncthreads();
      int c16 = tid & 15, ks32 = tid >> 4;
      float ph = 0.f;
      #pragma unroll
      for (int k = ks32 * 8; k < ks32 * 8 + 8; k++) ph += cf[k] * Wa1L[k * 16 + c16];
      red2[tid] = ph;
      __syncthreads();
      if (tid < 16) {
        float s = 0.f;
        for (int j = 0; j < 32; j++) s += red2[j * 16 + tid];
        int hc = i * 16 + tid;
        float hv = geluf(s + p.ba1[hc]);
        p.hbuf[b * 512 + hc] = hv;
        p.Hall[(size_t)((b << 7) + t) * 512 + hc] = hv;
      }
    }
    mini_sync(mb);  // MB7
    // --- fg / mod ---
    if (t < T - 1) {
      int c = tid & 7, ks = tid >> 3;
      const float* h = p.hbuf + b * 512;
      int cg = i * 8 + c;
      float pf = 0.f;
      #pragma unroll
      for (int k = ks * 8; k < ks * 8 + 8; k++) pf += h[k] * p.M2[k * 256 + cg];
      red2[tid] = pf;
      __syncthreads();
      if (tid < 8) {
        float s = 0.f;
        for (int j = 0; j < 64; j++) s += red2[j * 8 + tid];
        int cg2 = i * 8 + tid;
        int o = ((b << 7) + t + 1) * 256 + cg2;
        float fg = sigm(s + p.cvec3[cg2] + p.pW[o]);
        p.mod[b * 256 + cg2] = p.P[o] * (1.f + fg);
      }
    }
    grid_sync(gb);
  }
}

// final: out[bt, v] = Hall[bt,:] @ Wa2 + ba2
__global__ __launch_bounds__(256) void k_logits(const float* __restrict__ Hall,
                                                const float* __restrict__ Wa2,
                                                const float* __restrict__ ba2,
                                                float* __restrict__ out) {
  int rt = blockIdx.y;
  int v = blockIdx.x * 256 + threadIdx.x;
  const float* hrow = Hall + (size_t)rt * 32 * D2;
  float acc[32];
  float bb = ba2[v];
  #pragma unroll
  for (int r = 0; r < 32; r++) acc[r] = bb;
  for (int k = 0; k < D2; k++) {
    float w = Wa2[(size_t)k * V + v];
    #pragma unroll
    for (int r = 0; r < 32; r++) acc[r] += hrow[r * D2 + k] * w;
  }
  for (int r = 0; r < 32; r++) out[(size_t)(rt * 32 + r) * V + v] = acc[r];
}

// ---------------- launcher ----------------

extern "C" void kernel_launch(void* const* d_in, const int* in_sizes, int n_in,
                              void* d_out, int out_size, void* d_ws, size_t ws_size,
                              hipStream_t stream) {
  const int* idx = (const int*)d_in[0];
  const float* emb = (const float*)d_in[1];
  const float* pos = (const float*)d_in[2];
  const float* Wsens = (const float*)d_in[3];
  const float* bsens = (const float*)d_in[4];
  const float* Wfb = (const float*)d_in[5];
  const float* bfb = (const float*)d_in[6];
  const float* Wfg = (const float*)d_in[7];
  const float* bfg = (const float*)d_in[8];
  const float* bind = (const float*)d_in[9];
  const float* anet = (const float*)d_in[10];
  const float* Wg = (const float*)d_in[11];
  const float* bg = (const float*)d_in[12];
  const float* Wc = (const float*)d_in[13];
  const float* bc = (const float*)d_in[14];
  const float* lng = (const float*)d_in[15];
  const float* lnb = (const float*)d_in[16];
  const float* cmix = (const float*)d_in[17];
  const float* aimp = (const float*)d_in[18];
  const float* Wq = (const float*)d_in[19];
  const float* bq = (const float*)d_in[20];
  const float* Wk = (const float*)d_in[21];
  const float* bk = (const float*)d_in[22];
  const float* Wv = (const float*)d_in[23];
  const float* bv = (const float*)d_in[24];
  const float* Wo = (const float*)d_in[25];
  const float* bo = (const float*)d_in[26];
  const float* Wmg = (const float*)d_in[27];
  const float* bmg = (const float*)d_in[28];
  const float* mlng = (const float*)d_in[29];
  const float* mlnb = (const float*)d_in[30];
  const float* Wa1 = (const float*)d_in[31];
  const float* ba1 = (const float*)d_in[32];
  const float* Wa2 = (const float*)d_in[33];
  const float* ba2 = (const float*)d_in[34];

  float* ws = (float*)d_ws;
  float* M2 = ws;                   // 131072
  float* WoMg = ws + 131072;        // 65536
  float* cvec = ws + 196608;        // 256
  float* cvec2 = ws + 196864;       // 256
  float* cvec3 = ws + 197120;       // 256
  float* cvec4 = ws + 197376;       // 256
  float* iw = ws + 197632;          // 64
  float* cwb = ws + 197696;         // 64
  float* sigbind = ws + 197760;     // 4096
  float* P = ws + 201856;           // 262144
  float* pW = ws + 464000;          // 262144
  float* agents = ws + 726144;      // 131072
  float* X = ws + 857216;           // 786432
  float* psumU = ws + 1643648;      // 65536
  float* consbuf = ws + 1709184;    // 2048
  float* qbuf = ws + 1711232;       // 2048
  float* scorebuf = ws + 1713280;   // 4096
  float* recbuf = ws + 1717376;     // 2048
  float* valps = ws + 1719424;      // 512
  float* cfbuf = ws + 1719936;      // 2048
  float* hbuf = ws + 1721984;       // 4096
  float* mod = ws + 1726080;        // 2048
  float* Kc = ws + 1728128;         // 262144
  float* Vc = ws + 1990272;         // 262144
  float* Hall = ws + 2252416;       // 524288
  float* M = ws + 2776704;          // 131072
  float* Mpart = ws + 2907776;      // 1048576
  unsigned* bars = (unsigned*)(ws + 3956352);  // 1024 uints; end ~15.8 MB

  k_setup<<<1, 256, 0, stream>>>(aimp, cmix, bind, iw, cwb, sigbind);
  k_percepts<<<dim3((B * T * D + 255) / 256), 256, 0, stream>>>(idx, emb, pos, P);
  k_cvec<<<256, 256, 0, stream>>>(Wfb, ba2, bfb, cvec);
  k_mpart<<<dim3(8, 16), 256, 0, stream>>>(Wa2, Wfb, Mpart);
  k_mreduce<<<512, 256, 0, stream>>>(Mpart, M);
  k_gemmK256<<<64, 256, 0, stream>>>(M, Wfg, M2, 512);
  k_gemmK256<<<32, 256, 0, stream>>>(Wo, Wmg + 65536, WoMg, 256);
  k_gemmK256<<<128, 256, 0, stream>>>(P, Wfg + 65536, pW, 1024);
  k_vecmat<<<1, 256, 0, stream>>>(bo, Wmg + 65536, bmg, cvec2);
  k_vecmat<<<1, 256, 0, stream>>>(cvec, Wfg, bfg, cvec3);
  k_vecmat<<<1, 256, 0, stream>>>(bfb, Wfg, bfg, cvec4);
  k_barinit<<<4, 256, 0, stream>>>(bars);

  PP prm;
  prm.Wsens = Wsens; prm.bsens = bsens; prm.sigbind = sigbind; prm.anet = anet;
  prm.Wc = Wc; prm.bc = bc; prm.Wg = Wg; prm.bg = bg; prm.lng = lng; prm.lnb = lnb;
  prm.cw = cwb; prm.iw = iw; prm.Wq = Wq; prm.bq = bq; prm.Wk = Wk; prm.bk = bk;
  prm.Wv = Wv; prm.bv = bv; prm.Wo = Wo; prm.bo = bo; prm.Wmg = Wmg; prm.WoMg = WoMg;
  prm.cvec2 = cvec2; prm.mlng = mlng; prm.mlnb = mlnb; prm.Wa1 = Wa1; prm.ba1 = ba1;
  prm.M2 = M2; prm.cvec3 = cvec3; prm.cvec4 = cvec4; prm.P = P; prm.pW = pW;
  prm.agents = agents; prm.X = X; prm.psumU = psumU; prm.consbuf = consbuf;
  prm.qbuf = qbuf; prm.scorebuf = scorebuf; prm.recbuf = recbuf; prm.valps = valps;
  prm.cfbuf = cfbuf; prm.hbuf = hbuf; prm.mod = mod; prm.Kc = Kc; prm.Vc = Vc;
  prm.Hall = Hall; prm.bars = bars;

  void* args[] = {&prm};
  hipLaunchCooperativeKernel((void*)k_persist, dim3(256), dim3(512), args, 0, stream);

  k_logits<<<dim3(125, 32), 256, 0, stream>>>(Hall, Wa2, ba2, (float*)d_out);
}

// Round 4
// 26839.792 us; speedup vs baseline: 2.7532x; 1.1162x over previous
//
#include <hip/hip_runtime.h>
#include <math.h>

#define DEV __device__ __forceinline__

constexpr int B = 8, T = 128, V = 32000, A = 64, D = 256, NS = 16, S = 128, H = 4, HD = 64;
constexpr int D2 = 512;

DEV float sigm(float x) { return 1.0f / (1.0f + expf(-x)); }
DEV float geluf(float x) { return 0.5f * x * (1.0f + erff(x * 0.7071067811865476f)); }

DEV float4 f4z() { return make_float4(0.f, 0.f, 0.f, 0.f); }
DEV float4 ld4(const float* s) { return *(const float4*)s; }
DEV void st4(float* d, float4 v) { *(float4*)d = v; }
DEV float4 fma4(float a, float4 b, float4 c) {
  c.x += a * b.x; c.y += a * b.y; c.z += a * b.z; c.w += a * b.w; return c;
}
DEV float4 add4(float4 a, float4 b) {
  a.x += b.x; a.y += b.y; a.z += b.z; a.w += b.w; return a;
}
DEV float4 shflx4(float4 v, int m) {
  v.x = __shfl_xor(v.x, m, 64); v.y = __shfl_xor(v.y, m, 64);
  v.z = __shfl_xor(v.z, m, 64); v.w = __shfl_xor(v.w, m, 64); return v;
}

// ---------------- setup kernels ----------------

__global__ __launch_bounds__(256) void k_setup(const float* __restrict__ aimp,
                                               const float* __restrict__ cmix,
                                               const float* __restrict__ bind,
                                               const float* __restrict__ bsens,
                                               float* __restrict__ iw, float* __restrict__ cwv,
                                               float* __restrict__ sigbind,
                                               float* __restrict__ bs2) {
  int tid = threadIdx.x;
  if (tid < 64) {
    float v = aimp[tid];
    float m = v;
    #pragma unroll
    for (int o = 32; o > 0; o >>= 1) m = fmaxf(m, __shfl_xor(m, o, 64));
    float e = expf(v - m);
    float s = e;
    #pragma unroll
    for (int o = 32; o > 0; o >>= 1) s += __shfl_xor(s, o, 64);
    iw[tid] = e / s;
  }
  if (tid == 0) {
    float a = cmix[0], b = cmix[1], m = fmaxf(a, b);
    float ea = expf(a - m), eb = expf(b - m);
    cwv[0] = ea / (ea + eb);
    cwv[1] = eb / (ea + eb);
  }
  for (int i = tid; i < NS * D; i += 256) {
    float sb = sigm(bind[i]);
    sigbind[i] = sb;
    bs2[i] = bsens[i] * sb;
  }
}

__global__ __launch_bounds__(256) void k_percepts(const int* __restrict__ idx,
                                                  const float* __restrict__ emb,
                                                  const float* __restrict__ pos,
                                                  float* __restrict__ P) {
  int i = blockIdx.x * 256 + threadIdx.x;
  if (i < B * T * D) {
    int d = i & (D - 1);
    int bt = i / D;
    int t = bt & (T - 1);
    P[i] = emb[(size_t)idx[bt] * D + d] + pos[t * D + d];
  }
}

__global__ __launch_bounds__(256) void k_cvec_part(const float* __restrict__ Wfb,
                                                   const float* __restrict__ ba2,
                                                   float* __restrict__ part) {
  int p = blockIdx.x, tid = threadIdx.x;
  int v0 = p * 256;
  float acc = 0.f;
  for (int vv = 0; vv < 256; vv++) acc += ba2[v0 + vv] * Wfb[(size_t)(v0 + vv) * D + tid];
  part[p * 256 + tid] = acc;
}

__global__ __launch_bounds__(256) void k_cvec_red(const float* __restrict__ part,
                                                  const float* __restrict__ bfb,
                                                  float* __restrict__ cvec) {
  int tid = threadIdx.x;
  float s = 0.f;
  for (int p = 0; p < 125; p++) s += part[p * 256 + tid];
  cvec[tid] = s + bfb[tid];
}

__global__ __launch_bounds__(256) void k_mpart(const float* __restrict__ Wa2,
                                               const float* __restrict__ Wfb,
                                               float* __restrict__ part) {
  int it = blockIdx.y;
  int vc = blockIdx.x;
  int j = threadIdx.x;
  int i0 = it * 32, v0 = vc * 4000;
  __shared__ float a_l[32 * 125];
  float acc[32];
  #pragma unroll
  for (int r = 0; r < 32; r++) acc[r] = 0.f;
  for (int vb = 0; vb < 4000; vb += 125) {
    for (int l = threadIdx.x; l < 32 * 125; l += 256) {
      int r = l / 125, c = l - r * 125;
      a_l[l] = Wa2[(size_t)(i0 + r) * V + v0 + vb + c];
    }
    __syncthreads();
    for (int c = 0; c < 125; c++) {
      float w = Wfb[(size_t)(v0 + vb + c) * D + j];
      #pragma unroll
      for (int r = 0; r < 32; r++) acc[r] += a_l[r * 125 + c] * w;
    }
    __syncthreads();
  }
  for (int r = 0; r < 32; r++) part[((size_t)vc * D2 + i0 + r) * D + j] = acc[r];
}

__global__ __launch_bounds__(256) void k_mreduce(const float* __restrict__ part,
                                                 float* __restrict__ M) {
  int i = blockIdx.x, j = threadIdx.x;
  float s = 0.f;
  for (int vc = 0; vc < 8; vc++) s += part[((size_t)vc * D2 + i) * D + j];
  M[i * D + j] = s;
}

__global__ __launch_bounds__(256) void k_gemmK256(const float* __restrict__ Am,
                                                  const float* __restrict__ Bm,
                                                  float* __restrict__ C, int I) {
  int r0 = blockIdx.x * 8;
  int tid = threadIdx.x;
  __shared__ float a_l[8][256];
  for (int i = tid; i < 8 * 256; i += 256) a_l[i >> 8][i & 255] = Am[(r0 + (i >> 8)) * 256 + (i & 255)];
  __syncthreads();
  float acc[8] = {0, 0, 0, 0, 0, 0, 0, 0};
  for (int k = 0; k < 256; k++) {
    float bv = Bm[k * 256 + tid];
    #pragma unroll
    for (int r = 0; r < 8; r++) acc[r] += a_l[r][k] * bv;
  }
  for (int r = 0; r < 8; r++) C[(r0 + r) * 256 + tid] = acc[r];
}

__global__ __launch_bounds__(256) void k_vecmat(const float* __restrict__ a,
                                                const float* __restrict__ Bm,
                                                const float* __restrict__ bias,
                                                float* __restrict__ out) {
  int tid = threadIdx.x;
  __shared__ float a_l[256];
  a_l[tid] = a[tid];
  __syncthreads();
  float acc = 0.f;
  for (int k = 0; k < 256; k++) acc += a_l[k] * Bm[k * 256 + tid];
  out[tid] = acc + bias[tid];
}

// pack [Wc|Wg0|Wg1] slices: w6[s][k][m*32+cl], s = ch*8+ci
__global__ __launch_bounds__(256) void k_packw6(const float* __restrict__ Wc,
                                                const float* __restrict__ Wg,
                                                float* __restrict__ w6) {
  int s = blockIdx.x;
  int ch = s >> 3, ci = s & 7;
  for (int idx = threadIdx.x; idx < 256 * 96; idx += 256) {
    int k = idx / 96, cc = idx % 96;
    int m = cc >> 5, cl = cc & 31;
    int col = ci * 32 + cl;
    float v;
    if (m == 0) v = Wc[ch * 65536 + k * 256 + col];
    else if (m == 1) v = Wg[ch * 131072 + k * 256 + col];
    else v = Wg[ch * 131072 + (256 + k) * 256 + col];
    w6[s * 24576 + idx] = v;
  }
}

// WsT[col][k] = Wsens[k][col] * sigbind[col]   (tiled transpose)
__global__ __launch_bounds__(256) void k_packwst(const float* __restrict__ Wsens,
                                                 const float* __restrict__ sigbind,
                                                 float* __restrict__ wst) {
  __shared__ float tl[64][65];
  int c0 = blockIdx.x * 64, k0 = blockIdx.y * 64;
  for (int i = threadIdx.x; i < 4096; i += 256) {
    int kk = i >> 6, cc = i & 63;
    tl[kk][cc] = Wsens[(size_t)(k0 + kk) * 4096 + c0 + cc];
  }
  __syncthreads();
  for (int i = threadIdx.x; i < 4096; i += 256) {
    int cc = i >> 6, kk = i & 63;
    wst[(size_t)(c0 + cc) * 256 + k0 + kk] = tl[kk][cc] * sigbind[c0 + cc];
  }
}

__global__ __launch_bounds__(256) void k_packqp(const float* __restrict__ Wq,
                                                float* __restrict__ qp) {
  int h = blockIdx.x;
  for (int idx = threadIdx.x; idx < 64 * 256; idx += 256) {
    int c = idx >> 8, k = idx & 255;
    qp[(h * 64 + c) * 256 + k] = Wq[k * 256 + h * 64 + c];
  }
}

__global__ __launch_bounds__(256) void k_packomg(const float* __restrict__ Wo,
                                                 const float* __restrict__ Wmg,
                                                 const float* __restrict__ WoMg,
                                                 float* __restrict__ dst) {
  int j = blockIdx.x;
  for (int idx = threadIdx.x; idx < 256 * 96; idx += 256) {
    int k = idx / 96, cc = idx % 96;
    int m = cc >> 5, cl = cc & 31;
    int col = j * 32 + cl;
    float v;
    if (m == 0) v = Wo[k * 256 + col];
    else if (m == 1) v = Wmg[k * 256 + col];
    else v = WoMg[k * 256 + col];
    dst[j * 24576 + idx] = v;
  }
}

__global__ __launch_bounds__(256) void k_packcols(const float* __restrict__ src,
                                                  float* __restrict__ dst, int K, int C, int cpb) {
  int j = blockIdx.x;
  for (int idx = threadIdx.x; idx < K * cpb; idx += 256) {
    int k = idx / cpb, cl = idx % cpb;
    dst[(size_t)j * K * cpb + idx] = src[(size_t)k * C + j * cpb + cl];
  }
}

__global__ __launch_bounds__(256) void k_barinit(unsigned* bars) {
  int i = blockIdx.x * 256 + threadIdx.x;
  if (i < 8448) bars[i] = 0u;
}

// ---------------- barrier ----------------

DEV void fence_rel() { __builtin_amdgcn_fence(__ATOMIC_RELEASE, "agent"); }
DEV void fence_acq() { __builtin_amdgcn_fence(__ATOMIC_ACQUIRE, "agent"); }
DEV unsigned aload(const unsigned* p) { return __hip_atomic_load(p, __ATOMIC_RELAXED, __HIP_MEMORY_SCOPE_AGENT); }
DEV void astore(unsigned* p, unsigned v) { __hip_atomic_store(p, v, __ATOMIC_RELAXED, __HIP_MEMORY_SCOPE_AGENT); }

// flags: one padded slot per block (32 dwords apart); gen at [8192]
DEV void gbar(unsigned* flags, unsigned e) {
  __syncthreads();
  if (threadIdx.x == 0) {
    fence_rel();
    astore(&flags[blockIdx.x * 32], e);
  }
  if (blockIdx.x == 255) {
    if (threadIdx.x < 256) {
      unsigned spins = 0;
      while (aload(&flags[threadIdx.x * 32]) < e) {
        __builtin_amdgcn_s_sleep(2);
        if (++spins > (1u << 27)) break;
      }
    }
    __syncthreads();
    if (threadIdx.x == 0) {
      fence_acq();
      fence_rel();
      astore(&flags[8192], e);
    }
  }
  if (threadIdx.x == 0) {
    unsigned spins = 0;
    while (aload(&flags[8192]) < e) {
      __builtin_amdgcn_s_sleep(2);
      if (++spins > (1u << 27)) break;
    }
    fence_acq();
  }
  __syncthreads();
}

// ---------------- persistent kernel ----------------

struct PP {
  const float *w6pack, *wst, *bs2, *anet, *bc, *bg, *lng, *lnb, *cw, *iw;
  const float *wqp, *bq, *womgp, *bo, *cvec2, *mlng, *mlnb;
  const float *wkp, *bk, *wvp, *bv, *wa1p, *ba1, *m2p, *cvec3, *cvec4, *P, *pW;
  float *agents, *ubuf, *psumU, *consbuf, *recbuf, *valbuf, *valps;
  float *kvK, *kvV, *hbuf, *modbuf, *sensbuf, *Hall;
  unsigned* flags;
};

// LDS float offsets
#define MOD_OFF 0
#define RED_OFF 2048
#define BIG_OFF 3584
// G1
#define A_OFF 3584
#define X_OFF 20224
#define AN_OFF 26624
// att
#define KC_OFF 3584
#define VC_OFF 12288
#define WQ_OFF 20992
// out
#define WOMG_OFF 3584
#define RC_OFF 31232
#define CS_OFF 33280
// kc/vc
#define WKV_OFF 3584
#define KVAL_OFF 12800
#define KCF_OFF 14848
// hb
#define WA1_OFF 3584
#define HVAL_OFF 20992
#define HCF_OFF 23040
// mod
#define M2L_OFF 3584
#define HL_OFF 22016

#define TOTAL_LDS_F 37440

__global__ __launch_bounds__(512) void k_persist(PP p) {
  extern __shared__ float smf[];
  const int bid = blockIdx.x;
  const int tid = threadIdx.x;

  const bool isG1 = bid < 128;
  const bool isAtt = bid >= 128 && bid < 160;
  const bool isOut = bid >= 160 && bid < 168;
  const bool isKc = bid >= 168 && bid < 176;
  const bool isVc = bid >= 176 && bid < 184;
  const bool isHb = bid >= 184 && bid < 192;
  const bool isMod = bid >= 192 && bid < 200;

  const int g_b = bid >> 4;          // G1 batch
  const int g_ch = (bid >> 3) & 1;   // G1 channel
  const int g_ci = bid & 7;          // G1 col slice (32 D-cols)
  const int a_b = (bid - 128) >> 2;  // att batch
  const int a_h = bid & 3;           // att head
  const int jo = bid - 160, jk = bid - 168, jv = bid - 176, jh = bid - 184, jm = bid - 192;

  unsigned e = 1;

  // ---------- INIT ----------
  if (isG1) {
    for (int i = tid; i < 4096; i += 512) {
      int jr = i >> 6, l = i & 63;
      smf[AN_OFF + jr * 65 + l] = p.anet[g_ch * 4096 + i];
    }
    if (g_ch == 0) {
      for (int i = tid; i < 2048; i += 512) {
        int r = i >> 5, c = i & 31;
        p.agents[(g_b * 64 + r) * 256 + g_ci * 32 + c] = 0.f;
      }
    }
  } else if (isAtt) {
    for (int i = tid; i < 16384; i += 512) {
      int c = i >> 8, k = i & 255;
      smf[WQ_OFF + c * 257 + k] = p.wqp[(a_h * 64 + c) * 256 + k];
    }
  } else if (isOut) {
    for (int i = tid; i < 24576; i += 512) {
      int k = i / 96, cc = i % 96;
      smf[WOMG_OFF + k * 108 + cc] = p.womgp[jo * 24576 + i];
    }
  } else if (isKc) {
    for (int i = tid; i < 8192; i += 512) {
      int k = i >> 5, c = i & 31;
      smf[WKV_OFF + k * 36 + c] = p.wkp[jk * 8192 + i];
    }
  } else if (isVc) {
    for (int i = tid; i < 8192; i += 512) {
      int k = i >> 5, c = i & 31;
      smf[WKV_OFF + k * 36 + c] = p.wvp[jv * 8192 + i];
    }
  } else if (isHb) {
    for (int i = tid; i < 16384; i += 512) {
      int k = i >> 6, c = i & 63;
      smf[WA1_OFF + k * 68 + c] = p.wa1p[jh * 16384 + i];
    }
  } else if (isMod) {
    for (int i = tid; i < 16384; i += 512) {
      int k = i >> 5, c = i & 31;
      smf[M2L_OFF + k * 36 + c] = p.m2p[jm * 16384 + i];
    }
    if (tid < 256) {
      int bb = tid >> 5, c = jm * 32 + (tid & 31);
      int o = (bb * 128) * 256 + c;
      p.modbuf[bb * 256 + c] = p.P[o] * (1.f + sigm(p.cvec4[c] + p.pW[o]));
    }
  }
  gbar(p.flags, e++);

  // ---------- time loop ----------
  for (int t = 0; t < T; t++) {
    // ======== P1: sens on ALL blocks (16 cols each); att appends K/V slot t-1 ========
    {
      for (int i = tid; i < 512; i += 512)
        ((float4*)&smf[MOD_OFF])[i] = ((const float4*)p.modbuf)[i];
      if (isAtt && t >= 1) {
        // appended below after syncthreads (reads global kvK/kvV, writes own LDS)
      }
      __syncthreads();
      if (isAtt && t >= 1) {
        if (tid < 64) smf[KC_OFF + (t - 1) * 68 + tid] = p.kvK[a_b * 256 + a_h * 64 + tid];
        else if (tid < 128) smf[VC_OFF + (t - 1) * 68 + (tid - 64)] = p.kvV[a_b * 256 + a_h * 64 + tid - 64];
      }
      int c = tid >> 5, ks = tid & 31;
      int col = bid * 16 + c;
      float acc[8] = {0, 0, 0, 0, 0, 0, 0, 0};
      const float* wr = p.wst + (size_t)col * 256;
      #pragma unroll
      for (int kk = 0; kk < 8; kk++) {
        int k = ks + kk * 32;
        float w = wr[k];
        #pragma unroll
        for (int bb = 0; bb < 8; bb++) acc[bb] += w * smf[MOD_OFF + bb * 256 + k];
      }
      #pragma unroll
      for (int o = 1; o < 32; o <<= 1) {
        #pragma unroll
        for (int bb = 0; bb < 8; bb++) acc[bb] += __shfl_xor(acc[bb], o, 64);
      }
      if (ks == 0) {
        float bv = p.bs2[col];
        #pragma unroll
        for (int bb = 0; bb < 8; bb++) p.sensbuf[bb * 4096 + col] = acc[bb] + bv;
      }
    }
    gbar(p.flags, e++);

    // ======== P2: G1 — X = A'@W6, Y = anet@{Xc,Xg1}, u, psums ========
    float4 uA = f4z(), uB = f4z();
    if (isG1) {
      // stage A
      const float4* ag4 = (const float4*)(p.agents + g_b * A * D);
      #pragma unroll
      for (int i = 0; i < 8; i++) {
        int idx = i * 512 + tid;
        int r = idx >> 6, kq = idx & 63;
        st4(&smf[A_OFF + r * 260 + kq * 4], ag4[idx]);
      }
      __syncthreads();
      {
        const float4* sb4 = (const float4*)(p.sensbuf + g_b * 4096);
        for (int idx = tid; idx < 1024; idx += 512) {
          int r = idx >> 6, kq = idx & 63;
          float4 s = sb4[idx];
          float4 v = ld4(&smf[A_OFF + r * 260 + kq * 4]);
          st4(&smf[A_OFF + r * 260 + kq * 4], add4(v, s));
        }
      }
      __syncthreads();
      // X GEMM: thread (rq,cg,ks): rows rq*4..+4, col-quads {cg, 8+cg, 16+cg}, k = 4j+ks
      {
        int rq = tid >> 5, cg = (tid >> 2) & 7, ks = tid & 3;
        float4 acc[4][3];
        #pragma unroll
        for (int i = 0; i < 4; i++)
          #pragma unroll
          for (int m = 0; m < 3; m++) acc[i][m] = f4z();
        const float4* w4 = (const float4*)(p.w6pack + (size_t)(g_ch * 8 + g_ci) * 24576);
        for (int j = 0; j < 64; j++) {
          int k = 4 * j + ks;
          float4 w0 = w4[k * 24 + cg];
          float4 w1 = w4[k * 24 + 8 + cg];
          float4 w2 = w4[k * 24 + 16 + cg];
          #pragma unroll
          for (int i = 0; i < 4; i++) {
            float a = smf[A_OFF + (rq * 4 + i) * 260 + k];
            acc[i][0] = fma4(a, w0, acc[i][0]);
            acc[i][1] = fma4(a, w1, acc[i][1]);
            acc[i][2] = fma4(a, w2, acc[i][2]);
          }
        }
        #pragma unroll
        for (int pz = 0; pz < 4; pz++) {
          if (ks == pz) {
            #pragma unroll
            for (int i = 0; i < 4; i++)
              #pragma unroll
              for (int m = 0; m < 3; m++) {
                float* xp = &smf[X_OFF + (rq * 4 + i) * 100 + m * 32 + cg * 4];
                if (pz == 0) st4(xp, acc[i][m]);
                else st4(xp, add4(ld4(xp), acc[i][m]));
              }
          }
          __syncthreads();
        }
      }
      // Y GEMM + u
      {
        int rp = tid >> 4, cq = (tid >> 1) & 7, js = tid & 1;
        int r0 = rp * 2, r1 = r0 + 1;
        float4 yc0 = f4z(), yc1 = f4z(), yg0 = f4z(), yg1 = f4z();
        for (int jj = 0; jj < 32; jj++) {
          int j = js * 32 + jj;
          float a0 = smf[AN_OFF + r0 * 65 + j];
          float a1 = smf[AN_OFF + r1 * 65 + j];
          float4 xc = ld4(&smf[X_OFF + j * 100 + cq * 4]);
          float4 xg = ld4(&smf[X_OFF + j * 100 + 64 + cq * 4]);
          yc0 = fma4(a0, xc, yc0); yc1 = fma4(a1, xc, yc1);
          yg0 = fma4(a0, xg, yg0); yg1 = fma4(a1, xg, yg1);
        }
        yc0 = add4(yc0, shflx4(yc0, 1)); yc1 = add4(yc1, shflx4(yc1, 1));
        yg0 = add4(yg0, shflx4(yg0, 1)); yg1 = add4(yg1, shflx4(yg1, 1));
        float su0 = 0.f, sq0 = 0.f, su1 = 0.f, sq1 = 0.f;
        if (js == 0) {
          int c0 = g_ci * 32 + cq * 4;
          float4 x0A = ld4(&smf[X_OFF + r0 * 100 + 32 + cq * 4]);
          float4 x0B = ld4(&smf[X_OFF + r1 * 100 + 32 + cq * 4]);
          float4 aA = ld4(&smf[A_OFF + r0 * 260 + c0]);
          float4 aB = ld4(&smf[A_OFF + r1 * 260 + c0]);
          float4 bgv = ld4(p.bg + g_ch * 256 + c0);
          float4 bcv = ld4(p.bc + g_ch * 256 + c0);
          #define UC(res, yc, yg, xg0, av, bg_, bc_) { \
            float gate = sigm((xg0) + (yg) + (bg_)); \
            float cand = geluf((yc) + (bc_)); \
            res = gate * cand + (1.f - gate) * (av); }
          UC(uA.x, yc0.x, yg0.x, x0A.x, aA.x, bgv.x, bcv.x);
          UC(uA.y, yc0.y, yg0.y, x0A.y, aA.y, bgv.y, bcv.y);
          UC(uA.z, yc0.z, yg0.z, x0A.z, aA.z, bgv.z, bcv.z);
          UC(uA.w, yc0.w, yg0.w, x0A.w, aA.w, bgv.w, bcv.w);
          UC(uB.x, yc1.x, yg1.x, x0B.x, aB.x, bgv.x, bcv.x);
          UC(uB.y, yc1.y, yg1.y, x0B.y, aB.y, bgv.y, bcv.y);
          UC(uB.z, yc1.z, yg1.z, x0B.z, aB.z, bgv.z, bcv.z);
          UC(uB.w, yc1.w, yg1.w, x0B.w, aB.w, bgv.w, bcv.w);
          #undef UC
          st4(p.ubuf + g_ch * 131072 + g_b * 16384 + r0 * 256 + c0, uA);
          st4(p.ubuf + g_ch * 131072 + g_b * 16384 + r1 * 256 + c0, uB);
          su0 = uA.x + uA.y + uA.z + uA.w;
          sq0 = uA.x * uA.x + uA.y * uA.y + uA.z * uA.z + uA.w * uA.w;
          su1 = uB.x + uB.y + uB.z + uB.w;
          sq1 = uB.x * uB.x + uB.y * uB.y + uB.z * uB.z + uB.w * uB.w;
        }
        #pragma unroll
        for (int o = 2; o <= 8; o <<= 1) {
          su0 += __shfl_xor(su0, o, 64); sq0 += __shfl_xor(sq0, o, 64);
          su1 += __shfl_xor(su1, o, 64); sq1 += __shfl_xor(sq1, o, 64);
        }
        if (js == 0 && cq == 0) {
          int base = ((g_b * 2 + g_ch) * 8 + g_ci) * 128;
          p.psumU[base + r0 * 2] = su0; p.psumU[base + r0 * 2 + 1] = sq0;
          p.psumU[base + r1 * 2] = su1; p.psumU[base + r1 * 2 + 1] = sq1;
        }
      }
    }
    gbar(p.flags, e++);

    // ======== P3: G1-ch0 — LN stats, mix -> agents, cons ========
    if (isG1 && g_ch == 0) {
      if (tid < 128) {
        int c2 = tid >> 6, r = tid & 63;
        float s = 0.f, q = 0.f;
        const float* ps = p.psumU + ((g_b * 2 + c2) * 8) * 128 + r * 2;
        #pragma unroll
        for (int cc = 0; cc < 8; cc++) { s += ps[cc * 128]; q += ps[cc * 128 + 1]; }
        float mn = s * (1.f / 256.f), var = q * (1.f / 256.f) - mn * mn;
        smf[RED_OFF + 1024 + tid * 2] = mn;
        smf[RED_OFF + 1024 + tid * 2 + 1] = rsqrtf(var + 1e-5f);
      }
      __syncthreads();
      int rp = tid >> 4, cq = (tid >> 1) & 7, js = tid & 1;
      if (js == 0) {
        int r0 = rp * 2, r1 = r0 + 1;
        int c0 = g_ci * 32 + cq * 4;
        float4 v0 = ld4(p.ubuf + 131072 + g_b * 16384 + r0 * 256 + c0);
        float4 v1 = ld4(p.ubuf + 131072 + g_b * 16384 + r1 * 256 + c0);
        float m00 = smf[RED_OFF + 1024 + r0 * 2], rs00 = smf[RED_OFF + 1024 + r0 * 2 + 1];
        float m01 = smf[RED_OFF + 1024 + r1 * 2], rs01 = smf[RED_OFF + 1024 + r1 * 2 + 1];
        float m10 = smf[RED_OFF + 1024 + 128 + r0 * 2], rs10 = smf[RED_OFF + 1024 + 128 + r0 * 2 + 1];
        float m11 = smf[RED_OFF + 1024 + 128 + r1 * 2], rs11 = smf[RED_OFF + 1024 + 128 + r1 * 2 + 1];
        float4 g0 = ld4(p.lng + c0), b0 = ld4(p.lnb + c0);
        float4 g1 = ld4(p.lng + 256 + c0), b1 = ld4(p.lnb + 256 + c0);
        float cw0 = p.cw[0], cw1 = p.cw[1];
        float4 n0, n1;
        #define MIX(res, u0c, u1c, gc0, bc0, gc1, bc1, mA, rA, mB, rB) \
          res = cw0 * (((u0c) - mA) * rA * (gc0) + (bc0)) + cw1 * (((u1c) - mB) * rB * (gc1) + (bc1));
        MIX(n0.x, uA.x, v0.x, g0.x, b0.x, g1.x, b1.x, m00, rs00, m10, rs10);
        MIX(n0.y, uA.y, v0.y, g0.y, b0.y, g1.y, b1.y, m00, rs00, m10, rs10);
        MIX(n0.z, uA.z, v0.z, g0.z, b0.z, g1.z, b1.z, m00, rs00, m10, rs10);
        MIX(n0.w, uA.w, v0.w, g0.w, b0.w, g1.w, b1.w, m00, rs00, m10, rs10);
        MIX(n1.x, uB.x, v1.x, g0.x, b0.x, g1.x, b1.x, m01, rs01, m11, rs11);
        MIX(n1.y, uB.y, v1.y, g0.y, b0.y, g1.y, b1.y, m01, rs01, m11, rs11);
        MIX(n1.z, uB.z, v1.z, g0.z, b0.z, g1.z, b1.z, m01, rs01, m11, rs11);
        MIX(n1.w, uB.w, v1.w, g0.w, b0.w, g1.w, b1.w, m01, rs01, m11, rs11);
        #undef MIX
        st4(p.agents + (g_b * 64 + r0) * 256 + c0, n0);
        st4(p.agents + (g_b * 64 + r1) * 256 + c0, n1);
        float iw0 = p.iw[r0], iw1 = p.iw[r1];
        smf[RED_OFF + rp * 32 + cq * 4 + 0] = iw0 * n0.x + iw1 * n1.x;
        smf[RED_OFF + rp * 32 + cq * 4 + 1] = iw0 * n0.y + iw1 * n1.y;
        smf[RED_OFF + rp * 32 + cq * 4 + 2] = iw0 * n0.z + iw1 * n1.z;
        smf[RED_OFF + rp * 32 + cq * 4 + 3] = iw0 * n0.w + iw1 * n1.w;
      }
      __syncthreads();
      if (tid < 32) {
        float s = 0.f;
        #pragma unroll
        for (int rr = 0; rr < 32; rr++) s += smf[RED_OFF + rr * 32 + tid];
        p.consbuf[g_b * 256 + g_ci * 32 + tid] = s;
      }
    }
    gbar(p.flags, e++);

    // ======== P5: att — q, scores, softmax, rec ========
    if (isAtt) {
      if (tid < 64) ((float4*)&smf[RED_OFF])[tid] = ((const float4*)(p.consbuf + a_b * 256))[tid];
      __syncthreads();
      {
        int c = tid >> 3, ks = tid & 7;
        float acc = 0.f;
        #pragma unroll
        for (int kk = 0; kk < 32; kk++) {
          int k = ks + kk * 8;
          acc += smf[RED_OFF + k] * smf[WQ_OFF + c * 257 + k];
        }
        acc += __shfl_xor(acc, 1, 64);
        acc += __shfl_xor(acc, 2, 64);
        acc += __shfl_xor(acc, 4, 64);
        if (ks == 0) smf[RED_OFF + 256 + c] = acc + p.bq[a_h * 64 + c];
      }
      __syncthreads();
      if (t > 0) {
        {
          int s = tid >> 2, l4 = tid & 3;
          float a = 0.f;
          if (s < t) {
            #pragma unroll
            for (int i = 0; i < 16; i++) {
              int d = l4 * 16 + i;
              a += smf[RED_OFF + 256 + d] * smf[KC_OFF + s * 68 + d];
            }
          }
          a += __shfl_xor(a, 1, 64);
          a += __shfl_xor(a, 2, 64);
          if (s < t && l4 == 0) smf[RED_OFF + 320 + s] = a * 0.125f;
        }
        __syncthreads();
        if (tid < 64) {
          int s0 = tid, s1 = tid + 64;
          float v0 = (s0 < t) ? smf[RED_OFF + 320 + s0] : -1e30f;
          float v1 = (s1 < t) ? smf[RED_OFF + 320 + s1] : -1e30f;
          float m = fmaxf(v0, v1);
          #pragma unroll
          for (int o = 1; o < 64; o <<= 1) m = fmaxf(m, __shfl_xor(m, o, 64));
          float e0 = (s0 < t) ? expf(v0 - m) : 0.f;
          float e1 = (s1 < t) ? expf(v1 - m) : 0.f;
          float den = e0 + e1;
          #pragma unroll
          for (int o = 1; o < 64; o <<= 1) den += __shfl_xor(den, o, 64);
          float inv = 1.f / den;
          if (s0 < t) smf[RED_OFF + 448 + s0] = e0 * inv;
          if (s1 < t) smf[RED_OFF + 448 + s1] = e1 * inv;
        }
        __syncthreads();
        {
          int d = tid >> 3, ks = tid & 7;
          float a2 = 0.f;
          #pragma unroll
          for (int i = 0; i < 16; i++) {
            int s2 = i * 8 + ks;
            if (s2 < t) a2 += smf[RED_OFF + 448 + s2] * smf[VC_OFF + s2 * 68 + d];
          }
          a2 += __shfl_xor(a2, 1, 64);
          a2 += __shfl_xor(a2, 2, 64);
          a2 += __shfl_xor(a2, 4, 64);
          if (ks == 0) p.recbuf[a_b * 256 + a_h * 64 + d] = a2;
        }
      }
    }
    gbar(p.flags, e++);

    // ======== P6: out — o, mg, val, valps ========
    if (isOut && t > 0) {
      for (int i = tid; i < 512; i += 512) {
        ((float4*)&smf[RC_OFF])[i] = ((const float4*)p.recbuf)[i];
        ((float4*)&smf[CS_OFF])[i] = ((const float4*)p.consbuf)[i];
      }
      __syncthreads();
      int bb = tid >> 6, cq = (tid >> 3) & 7, ks = tid & 7;
      float4 ao = f4z(), am = f4z(), aw = f4z();
      #pragma unroll
      for (int kk = 0; kk < 32; kk++) {
        int k = ks + kk * 8;
        float rv = smf[RC_OFF + bb * 256 + k];
        float cv = smf[CS_OFF + bb * 256 + k];
        ao = fma4(rv, ld4(&smf[WOMG_OFF + k * 108 + cq * 4]), ao);
        am = fma4(cv, ld4(&smf[WOMG_OFF + k * 108 + 32 + cq * 4]), am);
        aw = fma4(rv, ld4(&smf[WOMG_OFF + k * 108 + 64 + cq * 4]), aw);
      }
      #pragma unroll
      for (int o = 1; o <= 4; o <<= 1) {
        ao = add4(ao, shflx4(ao, o)); am = add4(am, shflx4(am, o)); aw = add4(aw, shflx4(aw, o));
      }
      float sv = 0.f, sq = 0.f;
      if (ks == 0) {
        int c0 = jo * 32 + cq * 4;
        float4 bo4 = ld4(p.bo + c0), c2 = ld4(p.cvec2 + c0);
        float4 o4 = add4(ao, bo4);
        float4 mg;
        mg.x = sigm(am.x + aw.x + c2.x); mg.y = sigm(am.y + aw.y + c2.y);
        mg.z = sigm(am.z + aw.z + c2.z); mg.w = sigm(am.w + aw.w + c2.w);
        float4 cso = ld4(&smf[CS_OFF + bb * 256 + c0]);
        float4 val;
        val.x = cso.x + mg.x * o4.x; val.y = cso.y + mg.y * o4.y;
        val.z = cso.z + mg.z * o4.z; val.w = cso.w + mg.w * o4.w;
        st4(p.valbuf + bb * 256 + c0, val);
        sv = val.x + val.y + val.z + val.w;
        sq = val.x * val.x + val.y * val.y + val.z * val.z + val.w * val.w;
      }
      #pragma unroll
      for (int o = 8; o <= 32; o <<= 1) { sv += __shfl_xor(sv, o, 64); sq += __shfl_xor(sq, o, 64); }
      if (ks == 0 && cq == 0) {
        p.valps[bb * 16 + jo * 2] = sv;
        p.valps[bb * 16 + jo * 2 + 1] = sq;
      }
    }
    gbar(p.flags, e++);

    // ======== P8: kc/vc/hb — cf (redundant), then K/V/h ========
    if (isKc || isVc || isHb) {
      int VOFF = isHb ? HVAL_OFF : KVAL_OFF;
      int COFF = isHb ? HCF_OFF : KCF_OFF;
      const float4* src4 = (const float4*)((t > 0) ? p.valbuf : p.consbuf);
      ((float4*)&smf[VOFF])[tid] = src4[tid];
      __syncthreads();
      if (t > 0) {
        if (tid < 8) {
          float s = 0.f, q = 0.f;
          #pragma unroll
          for (int jj = 0; jj < 8; jj++) {
            s += p.valps[tid * 16 + jj * 2];
            q += p.valps[tid * 16 + jj * 2 + 1];
          }
          float mn = s * (1.f / 256.f), var = q * (1.f / 256.f) - mn * mn;
          smf[RED_OFF + tid * 2] = mn;
          smf[RED_OFF + tid * 2 + 1] = rsqrtf(var + 1e-5f);
        }
        __syncthreads();
        {
          float4 v = ((float4*)&smf[VOFF])[tid];
          int bb2 = tid >> 6, c0 = (tid & 63) * 4;
          float mn = smf[RED_OFF + bb2 * 2], rs = smf[RED_OFF + bb2 * 2 + 1];
          float4 g = ld4(p.mlng + c0), be = ld4(p.mlnb + c0);
          float4 cf;
          cf.x = (v.x - mn) * rs * g.x + be.x; cf.y = (v.y - mn) * rs * g.y + be.y;
          cf.z = (v.z - mn) * rs * g.z + be.z; cf.w = (v.w - mn) * rs * g.w + be.w;
          ((float4*)&smf[COFF])[tid] = cf;
        }
      } else {
        ((float4*)&smf[COFF])[tid] = ((float4*)&smf[VOFF])[tid];
      }
      __syncthreads();
      if (isKc || isVc) {
        int jj = isKc ? jk : jv;
        int bb = tid >> 6, cq = (tid >> 3) & 7, ks = tid & 7;
        float4 a = f4z();
        #pragma unroll
        for (int kk = 0; kk < 32; kk++) {
          int k = ks + kk * 8;
          a = fma4(smf[COFF + bb * 256 + k], ld4(&smf[WKV_OFF + k * 36 + cq * 4]), a);
        }
        #pragma unroll
        for (int o = 1; o <= 4; o <<= 1) a = add4(a, shflx4(a, o));
        if (ks == 0) {
          int c0 = jj * 32 + cq * 4;
          if (isKc) st4(p.kvK + bb * 256 + c0, add4(a, ld4(p.bk + c0)));
          else st4(p.kvV + bb * 256 + c0, add4(a, ld4(p.bv + c0)));
        }
      } else {  // hb
        int bb = tid >> 6, cq = (tid >> 2) & 15, ks = tid & 3;
        float4 a = f4z();
        #pragma unroll
        for (int kk = 0; kk < 64; kk++) {
          int k = ks + kk * 4;
          a = fma4(smf[COFF + bb * 256 + k], ld4(&smf[WA1_OFF + k * 68 + cq * 4]), a);
        }
        a = add4(a, shflx4(a, 1));
        a = add4(a, shflx4(a, 2));
        if (ks == 0) {
          int c0 = jh * 64 + cq * 4;
          float4 b4 = ld4(p.ba1 + c0);
          float4 hv;
          hv.x = geluf(a.x + b4.x); hv.y = geluf(a.y + b4.y);
          hv.z = geluf(a.z + b4.z); hv.w = geluf(a.w + b4.w);
          st4(p.hbuf + bb * 512 + c0, hv);
          st4(p.Hall + (size_t)(bb * 128 + t) * 512 + c0, hv);
        }
      }
    }
    gbar(p.flags, e++);

    // ======== P9: mod — fg, next mod ========
    if (isMod && t < T - 1) {
      for (int i = tid; i < 1024; i += 512)
        ((float4*)&smf[HL_OFF])[i] = ((const float4*)p.hbuf)[i];
      __syncthreads();
      int bb = tid >> 6, cq = (tid >> 3) & 7, ks = tid & 7;
      float4 a = f4z();
      #pragma unroll
      for (int kk = 0; kk < 64; kk++) {
        int k = ks + kk * 8;
        a = fma4(smf[HL_OFF + bb * 512 + k], ld4(&smf[M2L_OFF + k * 36 + cq * 4]), a);
      }
      #pragma unroll
      for (int o = 1; o <= 4; o <<= 1) a = add4(a, shflx4(a, o));
      if (ks == 0) {
        int c0 = jm * 32 + cq * 4;
        float4 c3 = ld4(p.cvec3 + c0);
        float4 pw = ld4(p.pW + (size_t)(bb * 128 + t + 1) * 256 + c0);
        float4 pt = ld4(p.P + (size_t)(bb * 128 + t + 1) * 256 + c0);
        float4 md;
        md.x = pt.x * (1.f + sigm(a.x + c3.x + pw.x));
        md.y = pt.y * (1.f + sigm(a.y + c3.y + pw.y));
        md.z = pt.z * (1.f + sigm(a.z + c3.z + pw.z));
        md.w = pt.w * (1.f + sigm(a.w + c3.w + pw.w));
        st4(p.modbuf + bb * 256 + c0, md);
      }
    }
    gbar(p.flags, e++);
  }
}

// ---------------- logits ----------------

__global__ __launch_bounds__(256) void k_logits(const float* __restrict__ Hall,
                                                const float* __restrict__ Wa2,
                                                const float* __restrict__ ba2,
                                                float* __restrict__ out) {
  int rt = blockIdx.y;
  int v = blockIdx.x * 256 + threadIdx.x;
  const float* hrow = Hall + (size_t)rt * 32 * D2;
  float acc[32];
  float bb = ba2[v];
  #pragma unroll
  for (int r = 0; r < 32; r++) acc[r] = bb;
  for (int k = 0; k < D2; k++) {
    float w = Wa2[(size_t)k * V + v];
    #pragma unroll
    for (int r = 0; r < 32; r++) acc[r] += hrow[r * D2 + k] * w;
  }
  for (int r = 0; r < 32; r++) out[(size_t)(rt * 32 + r) * V + v] = acc[r];
}

// ---------------- launcher ----------------

extern "C" void kernel_launch(void* const* d_in, const int* in_sizes, int n_in,
                              void* d_out, int out_size, void* d_ws, size_t ws_size,
                              hipStream_t stream) {
  const int* idx = (const int*)d_in[0];
  const float* emb = (const float*)d_in[1];
  const float* pos = (const float*)d_in[2];
  const float* Wsens = (const float*)d_in[3];
  const float* bsens = (const float*)d_in[4];
  const float* Wfb = (const float*)d_in[5];
  const float* bfb = (const float*)d_in[6];
  const float* Wfg = (const float*)d_in[7];
  const float* bfg = (const float*)d_in[8];
  const float* bind = (const float*)d_in[9];
  const float* anet = (const float*)d_in[10];
  const float* Wg = (const float*)d_in[11];
  const float* bg = (const float*)d_in[12];
  const float* Wc = (const float*)d_in[13];
  const float* bc = (const float*)d_in[14];
  const float* lng = (const float*)d_in[15];
  const float* lnb = (const float*)d_in[16];
  const float* cmix = (const float*)d_in[17];
  const float* aimp = (const float*)d_in[18];
  const float* Wq = (const float*)d_in[19];
  const float* bq = (const float*)d_in[20];
  const float* Wk = (const float*)d_in[21];
  const float* bk = (const float*)d_in[22];
  const float* Wv = (const float*)d_in[23];
  const float* bv = (const float*)d_in[24];
  const float* Wo = (const float*)d_in[25];
  const float* bo = (const float*)d_in[26];
  const float* Wmg = (const float*)d_in[27];
  const float* bmg = (const float*)d_in[28];
  const float* mlng = (const float*)d_in[29];
  const float* mlnb = (const float*)d_in[30];
  const float* Wa1 = (const float*)d_in[31];
  const float* ba1 = (const float*)d_in[32];
  const float* Wa2 = (const float*)d_in[33];
  const float* ba2 = (const float*)d_in[34];

  float* ws = (float*)d_ws;
  float* M2 = ws + 0;
  float* WoMg = ws + 131072;
  float* cvec = ws + 196608;
  float* cvec2 = ws + 196864;
  float* cvec3 = ws + 197120;
  float* cvec4 = ws + 197376;
  float* iw = ws + 197632;
  float* cwb = ws + 197696;
  float* sigbind = ws + 197760;
  float* bs2 = ws + 201856;
  float* P = ws + 205952;
  float* pW = ws + 468096;
  float* agents = ws + 730240;
  float* ubuf = ws + 861312;
  float* psumU = ws + 1123456;
  float* consbuf = ws + 1139840;
  float* recbuf = ws + 1141888;
  float* valbuf = ws + 1143936;
  float* valps = ws + 1145984;
  float* kvK = ws + 1146112;
  float* kvV = ws + 1148160;
  float* hbuf = ws + 1150208;
  float* modbuf = ws + 1154304;
  float* sensbuf = ws + 1156352;
  float* Hall = ws + 1189120;
  float* M = ws + 1713408;
  float* Mpart = ws + 1844480;
  float* w6pack = ws + 2893056;
  float* wst = ws + 3286272;
  float* wqp = ws + 4334848;
  float* womgp = ws + 4400384;
  float* wkp = ws + 4596992;
  float* wvp = ws + 4662528;
  float* wa1p = ws + 4728064;
  float* m2p = ws + 4859136;
  float* cvpart = ws + 4990208;
  unsigned* flags = (unsigned*)(ws + 5022208);

  k_setup<<<1, 256, 0, stream>>>(aimp, cmix, bind, bsens, iw, cwb, sigbind, bs2);
  k_percepts<<<dim3((B * T * D + 255) / 256), 256, 0, stream>>>(idx, emb, pos, P);
  k_cvec_part<<<125, 256, 0, stream>>>(Wfb, ba2, cvpart);
  k_cvec_red<<<1, 256, 0, stream>>>(cvpart, bfb, cvec);
  k_mpart<<<dim3(8, 16), 256, 0, stream>>>(Wa2, Wfb, Mpart);
  k_mreduce<<<512, 256, 0, stream>>>(Mpart, M);
  k_gemmK256<<<64, 256, 0, stream>>>(M, Wfg, M2, 512);
  k_gemmK256<<<32, 256, 0, stream>>>(Wo, Wmg + 65536, WoMg, 256);
  k_gemmK256<<<128, 256, 0, stream>>>(P, Wfg + 65536, pW, 1024);
  k_vecmat<<<1, 256, 0, stream>>>(bo, Wmg + 65536, bmg, cvec2);
  k_vecmat<<<1, 256, 0, stream>>>(cvec, Wfg, bfg, cvec3);
  k_vecmat<<<1, 256, 0, stream>>>(bfb, Wfg, bfg, cvec4);
  k_packw6<<<16, 256, 0, stream>>>(Wc, Wg, w6pack);
  k_packwst<<<dim3(64, 4), 256, 0, stream>>>(Wsens, sigbind, wst);
  k_packqp<<<4, 256, 0, stream>>>(Wq, wqp);
  k_packomg<<<8, 256, 0, stream>>>(Wo, Wmg, WoMg, womgp);
  k_packcols<<<8, 256, 0, stream>>>(Wk, wkp, 256, 256, 32);
  k_packcols<<<8, 256, 0, stream>>>(Wv, wvp, 256, 256, 32);
  k_packcols<<<8, 256, 0, stream>>>(Wa1, wa1p, 256, 512, 64);
  k_packcols<<<8, 256, 0, stream>>>(M2, m2p, 512, 256, 32);
  k_barinit<<<33, 256, 0, stream>>>(flags);

  PP prm;
  prm.w6pack = w6pack; prm.wst = wst; prm.bs2 = bs2; prm.anet = anet;
  prm.bc = bc; prm.bg = bg; prm.lng = lng; prm.lnb = lnb; prm.cw = cwb; prm.iw = iw;
  prm.wqp = wqp; prm.bq = bq; prm.womgp = womgp; prm.bo = bo; prm.cvec2 = cvec2;
  prm.mlng = mlng; prm.mlnb = mlnb; prm.wkp = wkp; prm.bk = bk; prm.wvp = wvp;
  prm.bv = bv; prm.wa1p = wa1p; prm.ba1 = ba1; prm.m2p = m2p; prm.cvec3 = cvec3;
  prm.cvec4 = cvec4; prm.P = P; prm.pW = pW;
  prm.agents = agents; prm.ubuf = ubuf; prm.psumU = psumU; prm.consbuf = consbuf;
  prm.recbuf = recbuf; prm.valbuf = valbuf; prm.valps = valps;
  prm.kvK = kvK; prm.kvV = kvV; prm.hbuf = hbuf; prm.modbuf = modbuf;
  prm.sensbuf = sensbuf; prm.Hall = Hall; prm.flags = flags;

  static bool attr_set = false;
  (void)attr_set;
  hipFuncSetAttribute((const void*)k_persist, hipFuncAttributeMaxDynamicSharedMemorySize,
                      TOTAL_LDS_F * 4);

  void* args[] = {&prm};
  hipLaunchCooperativeKernel((void*)k_persist, dim3(256), dim3(512), args,
                             TOTAL_LDS_F * 4, stream);

  k_logits<<<dim3(125, 32), 256, 0, stream>>>(Hall, Wa2, ba2, (float*)d_out);
}